// Round 10
// baseline (7234.338 us; speedup 1.0000x reference)
//
#include <hip/hip_runtime.h>
#include <hip/hip_bf16.h>
#include <math.h>

// B=8, S=128; D=512; H=8, HD=64; L=2; steps=20 (fixed).
// 8 groups (=batches) x 32 blocks, 3 phases / 3 group barriers per iter:
//   A: LN1+QKV+attention+O·Wo split-K partial -> atomic into hAcc (8 blk/grp)
//   C: LN2(local stats)+FFN1+ReLU                               (32 blk/grp)
//   D: FFN2+tanh-lerp dual-write + next-iter LN1 sum atomics    (16 blk/grp)
// All K-loops: double-buffered global_load_lds DMA (XOR swizzle) + register
// A-prefetch, so slab k+1 is in flight during slab k's MFMA burst.
#define NTOK 1024
#define DM   512
#define NB   256

typedef unsigned short u16;
typedef __attribute__((ext_vector_type(8))) short short8;
typedef __attribute__((ext_vector_type(4))) float f32x4;
typedef __attribute__((address_space(1))) const void* as1cv;
typedef __attribute__((address_space(3))) void* as3v;

__device__ inline u16 f2bf(float f) {
  __hip_bfloat16 h = __float2bfloat16(f);
  return *reinterpret_cast<u16*>(&h);
}
__device__ inline float bf2f(u16 b) {
  union { unsigned u; float f; } x; x.u = (unsigned)b << 16; return x.f;
}
__device__ inline void split8(const float* v, short8& hi, short8& lo) {
#pragma unroll
  for (int j = 0; j < 8; j++) {
    u16 h = f2bf(v[j]);
    hi[j] = (short)h;
    lo[j] = (short)f2bf(v[j] - bf2f(h));
  }
}
__device__ __forceinline__ f32x4 MFMA(short8 a, short8 b, f32x4 c) {
  return __builtin_amdgcn_mfma_f32_16x16x32_bf16(a, b, c, 0, 0, 0);
}
__device__ __forceinline__ void atomAddF(float* p, float v) {
  __hip_atomic_fetch_add(p, v, __ATOMIC_RELAXED, __HIP_MEMORY_SCOPE_AGENT);
}

struct KArgs {
  const int* x;
  const float* tok; const float* pos;
  const float* W[6];
  const float* bias6[6];
  const float* ln1g; const float* ln1b; const float* ln2g; const float* ln2b;
  const float* hw; const float* hb;
  float* out;
  float* xe;
  float* hbuf0; float* hbuf1;   // ping-pong h (read / atomic-accum)
  u16* ffh; u16* ffl;
  u16* vT;                      // [8 grp][8 head][64 dim][128 key] bf16
  float* hm;
  u16* WTh[6]; u16* WTl[6];     // split-bf16 transposed weights [L,N,K]
  float* ln1sum;                // [41][8][128][2] row sums (x, x^2)
  unsigned* bar;
};

// LDS: one 48 KB arena, phase-dependent overlays (all uses separated by syncs)
#define SMEM_BYTES 49152

__device__ __forceinline__ void cbar(unsigned* ctr, unsigned target, int tid) {
  __syncthreads();
  if (tid == 0) {
    __hip_atomic_fetch_add(ctr, 1u, __ATOMIC_RELEASE, __HIP_MEMORY_SCOPE_AGENT);
    while (__hip_atomic_load(ctr, __ATOMIC_RELAXED, __HIP_MEMORY_SCOPE_AGENT) < target)
      __builtin_amdgcn_s_sleep(2);
    __builtin_amdgcn_fence(__ATOMIC_ACQUIRE, "agent");
  }
  __syncthreads();
}
__global__ void bar_init(unsigned* bar) { bar[threadIdx.x] = 0u; bar[256 + threadIdx.x] = 0u; }

// ---------------- DMA helpers (XOR swizzle; verified r9) ----------------
__device__ __forceinline__ void dmaW64(const u16* gbase, int K, int k0, u16* lds, int tid) {
  const int wave = tid >> 6, lane = tid & 63;
#pragma unroll
  for (int i = 0; i < 2; i++) {
    const int lc = wave * 128 + i * 64 + lane;
    const int n = lc >> 3, sl = lc & 7;
    const int c = sl ^ (n & 7);
    const u16* g = gbase + (size_t)n * K + k0 + c * 8;
    u16* dst = lds + (size_t)(wave * 128 + i * 64) * 8;
    __builtin_amdgcn_global_load_lds((as1cv)(const void*)g, (as3v)(void*)dst, 16, 0, 0);
  }
}
__device__ __forceinline__ int boff64(int n, int cp) { return n * 64 + ((cp ^ (n & 7)) << 3); }

__device__ __forceinline__ void dmaW32(const u16* gbase, int K, int k0, u16* lds, int tid) {
  const int wave = tid >> 6, lane = tid & 63;
  const int lc = wave * 64 + lane;
  const int p = lc >> 3, s3 = lc & 7;
  const int c3 = s3 ^ (p & 7);
  const int n = p * 2 + (c3 >> 2);
  const int c = c3 & 3;
  const u16* g = gbase + (size_t)n * K + k0 + c * 8;
  u16* dst = lds + (size_t)(wave * 64) * 8;
  __builtin_amdgcn_global_load_lds((as1cv)(const void*)g, (as3v)(void*)dst, 16, 0, 0);
}
__device__ __forceinline__ int boff32(int n, int cq) {
  const int c3 = ((n & 1) << 2) | cq;
  return ((n >> 1) << 6) + ((c3 ^ ((n >> 1) & 7)) << 3);
}

// per-row LN stats into LDS
__device__ void stats_rows(const float* src, float (*st)[2], int nrows, int tid) {
  const int wave = tid >> 6, lane = tid & 63;
  for (int r = wave; r < nrows; r += 4) {
    const float* row = src + (size_t)r * DM;
    float s = 0.f, sq = 0.f;
#pragma unroll
    for (int i = 0; i < 8; i++) { float v = row[lane + i * 64]; s += v; sq += v * v; }
#pragma unroll
    for (int o = 1; o < 64; o <<= 1) { s += __shfl_xor(s, o, 64); sq += __shfl_xor(sq, o, 64); }
    if (lane == 0) {
      float mu = s * (1.0f / 512.0f);
      float var = sq * (1.0f / 512.0f) - mu * mu;
      st[r][0] = mu; st[r][1] = rsqrtf(var + 1e-5f);
    }
  }
}

// ---------------------------------------------------------------------------
// Phase A: LN1+QKV (full 128 rows, one dbuf K-loop) + attention + O·Wo
// split-K partial, atomically accumulated into hAcc.
// ---------------------------------------------------------------------------
__device__ void phaseA2(const KArgs& a, int l, int head, int grp, const float* ln1,
                        const float* hR, float* hAcc, char* sm, int tid)
{
  const int wave = tid >> 6, lane = tid & 63;
  const int q = lane >> 4, r16 = lane & 15;
  const int wm = (wave >> 1) * 32, wn = (wave & 1) * 32;
  const size_t wOff = (size_t)l * 512 * 512;
  const size_t hOff = (size_t)head * 64 * 512;

  const float* lg = a.ln1g + l * 512;
  const float* lb = a.ln1b + l * 512;
  const u16* wz[6] = { a.WTh[0] + wOff + hOff, a.WTl[0] + wOff + hOff,
                       a.WTh[1] + wOff + hOff, a.WTl[1] + wOff + hOff,
                       a.WTh[2] + wOff + hOff, a.WTl[2] + wOff + hOff };
  u16* vT = a.vT + (size_t)(grp * 8 + head) * 64 * 128;
  u16* Bst = (u16*)sm;     // [2 dbuf][6 tensors][2048 u16]

  // row base for fi=0..3: covers all 128 rows across 4 waves
  int RB[4];
#pragma unroll
  for (int fi = 0; fi < 4; fi++) RB[fi] = (fi >> 1) * 64 + wm + (fi & 1) * 16;

  float mu[4], iv[4];
#pragma unroll
  for (int fi = 0; fi < 4; fi++) {
    const float sv = ln1[RB[fi] * 2 + r16 * 2];        // row = RB+r16
    const float sq = ln1[RB[fi] * 2 + r16 * 2 + 1];
    const float m = sv * (1.0f / 512.0f);
    mu[fi] = m;
    iv[fi] = rsqrtf(sq * (1.0f / 512.0f) - m * m + 1e-5f);
  }

  f32x4 aq[4][2] = {}, ak[4][2] = {}, av[4][2] = {};

  // prefetch raw A floats + ln gamma/beta for ks=0
  float4 rA[4][2], rB4[4][2], rg[2], rb[2], rg2[2], rb2[2];
#pragma unroll
  for (int fi = 0; fi < 4; fi++) {
    const float* hp = hR + (size_t)(RB[fi] + r16) * DM + q * 8;
    rA[fi][0] = *(const float4*)hp; rA[fi][1] = *(const float4*)(hp + 4);
  }
  rg[0] = *(const float4*)&lg[q * 8]; rg[1] = *(const float4*)&lg[q * 8 + 4];
  rb[0] = *(const float4*)&lb[q * 8]; rb[1] = *(const float4*)&lb[q * 8 + 4];
#pragma unroll
  for (int z2 = 0; z2 < 6; z2++) dmaW32(wz[z2], 512, 0, Bst + z2 * 2048, tid);

  for (int ks = 0; ks < 16; ks++) {
    __syncthreads();                       // slab ks resident; other buf free
    const int cur = (ks & 1) * 6 * 2048;
    if (ks + 1 < 16) {
      const int nxt = ((ks + 1) & 1) * 6 * 2048;
#pragma unroll
      for (int z2 = 0; z2 < 6; z2++) dmaW32(wz[z2], 512, (ks + 1) * 32, Bst + nxt + z2 * 2048, tid);
      const int kb = (ks + 1) * 32 + q * 8;
#pragma unroll
      for (int fi = 0; fi < 4; fi++) {
        const float* hp = hR + (size_t)(RB[fi] + r16) * DM + kb;
        rB4[fi][0] = *(const float4*)hp; rB4[fi][1] = *(const float4*)(hp + 4);
      }
      rg2[0] = *(const float4*)&lg[kb]; rg2[1] = *(const float4*)&lg[kb + 4];
      rb2[0] = *(const float4*)&lb[kb]; rb2[1] = *(const float4*)&lb[kb + 4];
    }
    // LN + split current slab's A-frags
    short8 ah[4], al[4];
#pragma unroll
    for (int fi = 0; fi < 4; fi++) {
      float v[8] = {
        (rA[fi][0].x - mu[fi]) * iv[fi] * rg[0].x + rb[0].x,
        (rA[fi][0].y - mu[fi]) * iv[fi] * rg[0].y + rb[0].y,
        (rA[fi][0].z - mu[fi]) * iv[fi] * rg[0].z + rb[0].z,
        (rA[fi][0].w - mu[fi]) * iv[fi] * rg[0].w + rb[0].w,
        (rA[fi][1].x - mu[fi]) * iv[fi] * rg[1].x + rb[1].x,
        (rA[fi][1].y - mu[fi]) * iv[fi] * rg[1].y + rb[1].y,
        (rA[fi][1].z - mu[fi]) * iv[fi] * rg[1].z + rb[1].z,
        (rA[fi][1].w - mu[fi]) * iv[fi] * rg[1].w + rb[1].w };
      split8(v, ah[fi], al[fi]);
    }
#pragma unroll
    for (int z = 0; z < 3; z++) {
      f32x4 (*ac)[2] = (z == 0) ? aq : ((z == 1) ? ak : av);
#pragma unroll
      for (int fj = 0; fj < 2; fj++) {
        const int n = wn + fj * 16 + r16;
        const int off = boff32(n, q);
        short8 bh = *(const short8*)&Bst[cur + (z * 2) * 2048 + off];
        short8 bl = *(const short8*)&Bst[cur + (z * 2 + 1) * 2048 + off];
#pragma unroll
        for (int fi = 0; fi < 4; fi++) {
          ac[fi][fj] = MFMA(ah[fi], bh, ac[fi][fj]);
          ac[fi][fj] = MFMA(ah[fi], bl, ac[fi][fj]);
          ac[fi][fj] = MFMA(al[fi], bh, ac[fi][fj]);
        }
      }
    }
#pragma unroll
    for (int fi = 0; fi < 4; fi++) { rA[fi][0] = rB4[fi][0]; rA[fi][1] = rB4[fi][1]; }
    rg[0] = rg2[0]; rg[1] = rg2[1]; rb[0] = rb2[0]; rb[1] = rb2[1];
  }
  __syncthreads();   // all MFMA done: Bst arena free for Q/K overlay

  u16 (*Qb)[66] = (u16(*)[66])sm;
  u16 (*Kb)[66] = (u16(*)[66])(sm + 16896);
  {
    const float* bq = a.bias6[0] + l * 512 + head * 64;
    const float* bk = a.bias6[1] + l * 512 + head * 64;
    const float* bv = a.bias6[2] + l * 512 + head * 64;
#pragma unroll
    for (int fi = 0; fi < 4; fi++) {
#pragma unroll
      for (int fj = 0; fj < 2; fj++) {
        const int col = wn + fj * 16 + r16;
        const int row0 = RB[fi] + q * 4;
        const float bqv = bq[col], bkv = bk[col], bvv = bv[col];
#pragma unroll
        for (int i = 0; i < 4; i++) {
          Qb[row0 + i][col] = f2bf(aq[fi][fj][i] + bqv);
          Kb[row0 + i][col] = f2bf(ak[fi][fj][i] + bkv);
          vT[(size_t)col * 128 + row0 + i] = f2bf(av[fi][fj][i] + bvv);
        }
      }
    }
  }
  __syncthreads();

  // scores S = Q K^T (wave: rows m0..m0+31 x 128 keys)
  const int m0 = wave * 32;
  f32x4 sc[2][8] = {};
#pragma unroll
  for (int kk = 0; kk < 2; kk++) {
    short8 aQ[2];
#pragma unroll
    for (int fi = 0; fi < 2; fi++)
      aQ[fi] = *(const short8*)&Qb[m0 + fi * 16 + r16][kk * 32 + q * 8];
#pragma unroll
    for (int nt = 0; nt < 8; nt++) {
      short8 bK = *(const short8*)&Kb[nt * 16 + r16][kk * 32 + q * 8];
#pragma unroll
      for (int fi = 0; fi < 2; fi++) sc[fi][nt] = MFMA(aQ[fi], bK, sc[fi][nt]);
    }
  }
  __syncthreads();   // Pb overlays Qb/Kb

  // register softmax
#pragma unroll
  for (int fi = 0; fi < 2; fi++) {
#pragma unroll
    for (int i = 0; i < 4; i++) {
      float mrow = -1e30f;
#pragma unroll
      for (int nt = 0; nt < 8; nt++) {
        float v = sc[fi][nt][i] * 0.125f; sc[fi][nt][i] = v; mrow = fmaxf(mrow, v);
      }
#pragma unroll
      for (int o = 1; o < 16; o <<= 1) mrow = fmaxf(mrow, __shfl_xor(mrow, o, 64));
      float lsum = 0.f;
#pragma unroll
      for (int nt = 0; nt < 8; nt++) {
        float p = __expf(sc[fi][nt][i] - mrow); sc[fi][nt][i] = p; lsum += p;
      }
#pragma unroll
      for (int o = 1; o < 16; o <<= 1) lsum += __shfl_xor(lsum, o, 64);
      const float inv = 1.0f / lsum;
#pragma unroll
      for (int nt = 0; nt < 8; nt++) sc[fi][nt][i] *= inv;
    }
  }
  u16 (*Pb)[132] = (u16(*)[132])sm;
#pragma unroll
  for (int fi = 0; fi < 2; fi++)
#pragma unroll
    for (int nt = 0; nt < 8; nt++)
#pragma unroll
      for (int i = 0; i < 4; i++)
        Pb[m0 + fi * 16 + q * 4 + i][nt * 16 + r16] = f2bf(sc[fi][nt][i]);
  __syncthreads();

  // O = P V
  f32x4 oa[2][4] = {};
#pragma unroll
  for (int kt = 0; kt < 4; kt++) {
    short8 aP[2];
#pragma unroll
    for (int fi = 0; fi < 2; fi++)
      aP[fi] = *(const short8*)&Pb[m0 + fi * 16 + r16][kt * 32 + q * 8];
#pragma unroll
    for (int nt = 0; nt < 4; nt++) {
      short8 bV = *(const short8*)(vT + (size_t)(nt * 16 + r16) * 128 + kt * 32 + q * 8);
#pragma unroll
      for (int fi = 0; fi < 2; fi++) oa[fi][nt] = MFMA(aP[fi], bV, oa[fi][nt]);
    }
  }
  __syncthreads();   // Oh/Ol overlay Pb

  // O -> LDS split hi/lo (A-layout source for O·Wo)
  u16 (*Oh)[66] = (u16(*)[66])sm;
  u16 (*Ol)[66] = (u16(*)[66])(sm + 16896);
#pragma unroll
  for (int fi = 0; fi < 2; fi++)
#pragma unroll
    for (int nt = 0; nt < 4; nt++)
#pragma unroll
      for (int i = 0; i < 4; i++) {
        const int row = m0 + fi * 16 + q * 4 + i;
        const int col = nt * 16 + r16;
        float v = oa[fi][nt][i];
        u16 hv = f2bf(v);
        Oh[row][col] = hv;
        Ol[row][col] = f2bf(v - bf2f(hv));
      }
  __syncthreads();

  // O·Wo split-K partial: contract k in [head*64, head*64+64), atomic into hAcc
  short8 aOh[2][2], aOl[2][2];   // [kk][fi]
#pragma unroll
  for (int kk = 0; kk < 2; kk++)
#pragma unroll
    for (int fi = 0; fi < 2; fi++) {
      aOh[kk][fi] = *(const short8*)&Oh[m0 + fi * 16 + r16][kk * 32 + q * 8];
      aOl[kk][fi] = *(const short8*)&Ol[m0 + fi * 16 + r16][kk * 32 + q * 8];
    }
  const u16* WoTh = a.WTh[3] + wOff;
  const u16* WoTl = a.WTl[3] + wOff;
  const float* bo = a.bias6[3] + l * 512;
  const int kbase = head * 64;
  for (int nt = 0; nt < 32; nt++) {
    f32x4 acc2[2] = {};
    const size_t nrow = (size_t)(nt * 16 + r16) * 512 + kbase + q * 8;
#pragma unroll
    for (int kk = 0; kk < 2; kk++) {
      short8 bh = *(const short8*)(WoTh + nrow + kk * 32);
      short8 bl = *(const short8*)(WoTl + nrow + kk * 32);
#pragma unroll
      for (int fi = 0; fi < 2; fi++) {
        acc2[fi] = MFMA(aOh[kk][fi], bh, acc2[fi]);
        acc2[fi] = MFMA(aOh[kk][fi], bl, acc2[fi]);
        acc2[fi] = MFMA(aOl[kk][fi], bh, acc2[fi]);
      }
    }
    const int col = nt * 16 + r16;
    const float bov = (head == 0) ? bo[col] : 0.0f;
#pragma unroll
    for (int fi = 0; fi < 2; fi++)
#pragma unroll
      for (int i = 0; i < 4; i++) {
        const int row = m0 + fi * 16 + q * 4 + i;
        atomAddF(&hAcc[(size_t)row * DM + col], acc2[fi][i] + bov);
      }
  }
}

// ---------------------------------------------------------------------------
// Phase C: LN2 (block-local stats) + FFN1 + ReLU. dbuf DMA, reg A-prefetch.
// ---------------------------------------------------------------------------
__device__ void phaseC(const KArgs& a, int l, const float* hAcc,
                       u16* ffh_g, u16* ffl_g, int bm, int bn, char* sm, int tid)
{
  u16* Bsh = (u16*)sm;                 // [2][4096]
  u16* Bsl = (u16*)(sm + 16384);       // [2][4096]
  float (*st)[2] = (float (*)[2])(sm + 32768);
  const int wave = tid >> 6, lane = tid & 63;
  const int q = lane >> 4, r16 = lane & 15;
  const int wm = (wave >> 1) * 32, wn = (wave & 1) * 32;
  const size_t fOff = (size_t)l * 512 * 1024;
  const float* lg = a.ln2g + l * 512;
  const float* lb = a.ln2b + l * 512;

  stats_rows(hAcc + (size_t)bm * DM, st, 64, tid);
  __syncthreads();
  float mu[2], iv[2];
#pragma unroll
  for (int fi = 0; fi < 2; fi++) {
    const int rr = wm + fi * 16 + r16;
    mu[fi] = st[rr][0]; iv[fi] = st[rr][1];
  }

  const u16* bh0 = a.WTh[4] + fOff + (size_t)bn * 512;
  const u16* bl0 = a.WTl[4] + fOff + (size_t)bn * 512;
  f32x4 acc[2][2] = {};

  float4 rA[2][2][2], rB4[2][2][2], rg[2][2], rb[2][2], rg2[2][2], rb2[2][2];
#pragma unroll
  for (int kk = 0; kk < 2; kk++) {
    const int kb = kk * 32 + q * 8;
#pragma unroll
    for (int fi = 0; fi < 2; fi++) {
      const float* hp = hAcc + (size_t)(bm + wm + fi * 16 + r16) * DM + kb;
      rA[kk][fi][0] = *(const float4*)hp; rA[kk][fi][1] = *(const float4*)(hp + 4);
    }
    rg[kk][0] = *(const float4*)&lg[kb]; rg[kk][1] = *(const float4*)&lg[kb + 4];
    rb[kk][0] = *(const float4*)&lb[kb]; rb[kk][1] = *(const float4*)&lb[kb + 4];
  }
  dmaW64(bh0, 512, 0, Bsh, tid);
  dmaW64(bl0, 512, 0, Bsl, tid);

  for (int ks = 0; ks < 8; ks++) {
    __syncthreads();
    const int cur = (ks & 1) * 4096;
    if (ks + 1 < 8) {
      const int nxt = ((ks + 1) & 1) * 4096;
      dmaW64(bh0, 512, (ks + 1) * 64, Bsh + nxt, tid);
      dmaW64(bl0, 512, (ks + 1) * 64, Bsl + nxt, tid);
#pragma unroll
      for (int kk = 0; kk < 2; kk++) {
        const int kb = (ks + 1) * 64 + kk * 32 + q * 8;
#pragma unroll
        for (int fi = 0; fi < 2; fi++) {
          const float* hp = hAcc + (size_t)(bm + wm + fi * 16 + r16) * DM + kb;
          rB4[kk][fi][0] = *(const float4*)hp; rB4[kk][fi][1] = *(const float4*)(hp + 4);
        }
        rg2[kk][0] = *(const float4*)&lg[kb]; rg2[kk][1] = *(const float4*)&lg[kb + 4];
        rb2[kk][0] = *(const float4*)&lb[kb]; rb2[kk][1] = *(const float4*)&lb[kb + 4];
      }
    }
#pragma unroll
    for (int kk = 0; kk < 2; kk++) {
      short8 ah[2], al[2];
#pragma unroll
      for (int fi = 0; fi < 2; fi++) {
        float v[8] = {
          (rA[kk][fi][0].x - mu[fi]) * iv[fi] * rg[kk][0].x + rb[kk][0].x,
          (rA[kk][fi][0].y - mu[fi]) * iv[fi] * rg[kk][0].y + rb[kk][0].y,
          (rA[kk][fi][0].z - mu[fi]) * iv[fi] * rg[kk][0].z + rb[kk][0].z,
          (rA[kk][fi][0].w - mu[fi]) * iv[fi] * rg[kk][0].w + rb[kk][0].w,
          (rA[kk][fi][1].x - mu[fi]) * iv[fi] * rg[kk][1].x + rb[kk][1].x,
          (rA[kk][fi][1].y - mu[fi]) * iv[fi] * rg[kk][1].y + rb[kk][1].y,
          (rA[kk][fi][1].z - mu[fi]) * iv[fi] * rg[kk][1].z + rb[kk][1].z,
          (rA[kk][fi][1].w - mu[fi]) * iv[fi] * rg[kk][1].w + rb[kk][1].w };
        split8(v, ah[fi], al[fi]);
      }
#pragma unroll
      for (int fj = 0; fj < 2; fj++) {
        const int n = wn + fj * 16 + r16;
        const int off = boff64(n, kk * 4 + q);
        short8 bh = *(const short8*)&Bsh[cur + off];
        short8 bl = *(const short8*)&Bsl[cur + off];
#pragma unroll
        for (int fi = 0; fi < 2; fi++) {
          acc[fi][fj] = MFMA(ah[fi], bh, acc[fi][fj]);
          acc[fi][fj] = MFMA(ah[fi], bl, acc[fi][fj]);
          acc[fi][fj] = MFMA(al[fi], bh, acc[fi][fj]);
        }
      }
    }
#pragma unroll
    for (int kk = 0; kk < 2; kk++) {
#pragma unroll
      for (int fi = 0; fi < 2; fi++) { rA[kk][fi][0] = rB4[kk][fi][0]; rA[kk][fi][1] = rB4[kk][fi][1]; }
      rg[kk][0] = rg2[kk][0]; rg[kk][1] = rg2[kk][1];
      rb[kk][0] = rb2[kk][0]; rb[kk][1] = rb2[kk][1];
    }
  }

  const float* b1 = a.bias6[4] + l * 1024;
#pragma unroll
  for (int fi = 0; fi < 2; fi++)
#pragma unroll
    for (int fj = 0; fj < 2; fj++) {
      const int col = bn + wn + fj * 16 + r16;
      const float bvv = b1[col];
      const int row0 = bm + wm + fi * 16 + q * 4;
#pragma unroll
      for (int i = 0; i < 4; i++) {
        const size_t off = (size_t)(row0 + i) * 1024 + col;
        float r = fmaxf(acc[fi][fj][i] + bvv, 0.f);
        u16 hv = f2bf(r);
        ffh_g[off] = hv; ffl_g[off] = f2bf(r - bf2f(hv));
      }
    }
}

// ---------------------------------------------------------------------------
// Phase D: FFN2 + tanh-lerp; dual-write next h buffers; fold next LN1 sums.
// ---------------------------------------------------------------------------
__device__ void phaseD(const KArgs& a, int l, const u16* ffh_g, const u16* ffl_g,
                       const float* hAcc, const float* xe_g,
                       float* hNR, float* hNA, float* ln1nx,
                       int bm, int bn, char* sm, int tid)
{
  u16* Bsh = (u16*)sm;
  u16* Bsl = (u16*)(sm + 16384);
  const int wave = tid >> 6, lane = tid & 63;
  const int q = lane >> 4, r16 = lane & 15;
  const int wm = (wave >> 1) * 32, wn = (wave & 1) * 32;
  const size_t fOff = (size_t)l * 512 * 1024;

  const u16* bh0 = a.WTh[5] + fOff + (size_t)bn * 1024;
  const u16* bl0 = a.WTl[5] + fOff + (size_t)bn * 1024;
  f32x4 acc[2][2] = {};

  short8 pah[2][2], pal[2][2], nah[2][2], nal[2][2];   // [kk][fi]
#pragma unroll
  for (int kk = 0; kk < 2; kk++)
#pragma unroll
    for (int fi = 0; fi < 2; fi++) {
      const size_t ao = (size_t)(bm + wm + fi * 16 + r16) * 1024 + kk * 32 + q * 8;
      pah[kk][fi] = *(const short8*)(ffh_g + ao);
      pal[kk][fi] = *(const short8*)(ffl_g + ao);
    }
  dmaW64(bh0, 1024, 0, Bsh, tid);
  dmaW64(bl0, 1024, 0, Bsl, tid);

  for (int ks = 0; ks < 16; ks++) {
    __syncthreads();
    const int cur = (ks & 1) * 4096;
    if (ks + 1 < 16) {
      const int nxt = ((ks + 1) & 1) * 4096;
      dmaW64(bh0, 1024, (ks + 1) * 64, Bsh + nxt, tid);
      dmaW64(bl0, 1024, (ks + 1) * 64, Bsl + nxt, tid);
#pragma unroll
      for (int kk = 0; kk < 2; kk++)
#pragma unroll
        for (int fi = 0; fi < 2; fi++) {
          const size_t ao = (size_t)(bm + wm + fi * 16 + r16) * 1024 + (ks + 1) * 64 + kk * 32 + q * 8;
          nah[kk][fi] = *(const short8*)(ffh_g + ao);
          nal[kk][fi] = *(const short8*)(ffl_g + ao);
        }
    }
#pragma unroll
    for (int kk = 0; kk < 2; kk++) {
#pragma unroll
      for (int fj = 0; fj < 2; fj++) {
        const int n = wn + fj * 16 + r16;
        const int off = boff64(n, kk * 4 + q);
        short8 bh = *(const short8*)&Bsh[cur + off];
        short8 bl = *(const short8*)&Bsl[cur + off];
#pragma unroll
        for (int fi = 0; fi < 2; fi++) {
          acc[fi][fj] = MFMA(pah[kk][fi], bh, acc[fi][fj]);
          acc[fi][fj] = MFMA(pah[kk][fi], bl, acc[fi][fj]);
          acc[fi][fj] = MFMA(pal[kk][fi], bh, acc[fi][fj]);
        }
      }
    }
#pragma unroll
    for (int kk = 0; kk < 2; kk++)
#pragma unroll
      for (int fi = 0; fi < 2; fi++) { pah[kk][fi] = nah[kk][fi]; pal[kk][fi] = nal[kk][fi]; }
  }

  const float* b2 = a.bias6[5] + l * 512;
  float outv[2][2][4];
#pragma unroll
  for (int fi = 0; fi < 2; fi++)
#pragma unroll
    for (int fj = 0; fj < 2; fj++) {
      const int col = bn + wn + fj * 16 + r16;
      const float bvv = b2[col];
      const int row0 = bm + wm + fi * 16 + q * 4;
#pragma unroll
      for (int i = 0; i < 4; i++) {
        const size_t off = (size_t)(row0 + i) * DM + col;
        const float hv = hAcc[off];
        const float hn = 0.5f * hv + 0.5f * tanhf(hv + acc[fi][fj][i] + bvv + xe_g[off]);
        hNR[off] = hn; hNA[off] = hn;
        outv[fi][fj][i] = hn;
      }
    }
  // fold next-iteration LN1 row sums
#pragma unroll
  for (int fi = 0; fi < 2; fi++)
#pragma unroll
    for (int i = 0; i < 4; i++) {
      float a0 = outv[fi][0][i], a1 = outv[fi][1][i];
      float s1 = a0 + a1, s2 = a0 * a0 + a1 * a1;
#pragma unroll
      for (int o = 1; o < 16; o <<= 1) { s1 += __shfl_xor(s1, o, 64); s2 += __shfl_xor(s2, o, 64); }
      if (r16 == 0) {
        const int row = bm + wm + fi * 16 + q * 4 + i;
        atomAddF(&ln1nx[row * 2], s1);
        atomAddF(&ln1nx[row * 2 + 1], s2);
      }
    }
}

// ---------------------------------------------------------------------------
__global__ __launch_bounds__(256, 1) void persist(KArgs a)
{
  __shared__ __align__(16) char smem[SMEM_BYTES];
  const int tid = threadIdx.x;
  const int bid = blockIdx.x;
  const int grp = bid & 7;
  const int gb  = bid >> 3;

  // ---- phase 0: weight split-transpose + embed + zero h bufs + LN sums ----
  {
    float (*tile)[33] = (float (*)[33])smem;
    const int tx = tid & 31, ty = tid >> 5;
    for (int t = bid; t < 4096; t += NB) {
      int tensor, z, k0, n0, K, N;
      if (t < 2048)      { tensor = t >> 9;  int rem = t & 511;  z = rem >> 8; int r2 = rem & 255;
                           K = 512;  N = 512;  k0 = (r2 >> 4) << 5; n0 = (r2 & 15) << 5; }
      else if (t < 3072) { tensor = 4;       int rem = t - 2048; z = rem >> 9; int r2 = rem & 511;
                           K = 512;  N = 1024; k0 = (r2 >> 5) << 5; n0 = (r2 & 31) << 5; }
      else               { tensor = 5;       int rem = t - 3072; z = rem >> 9; int r2 = rem & 511;
                           K = 1024; N = 512;  k0 = (r2 >> 4) << 5; n0 = (r2 & 15) << 5; }
      const float* src = a.W[tensor]   + (size_t)z * K * N;
      u16* dhi         = a.WTh[tensor] + (size_t)z * K * N;
      u16* dlo         = a.WTl[tensor] + (size_t)z * K * N;
      __syncthreads();
#pragma unroll
      for (int r = 0; r < 4; r++) {
        int k = ty + r * 8;
        tile[k][tx] = src[(size_t)(k0 + k) * N + n0 + tx];
      }
      __syncthreads();
#pragma unroll
      for (int r = 0; r < 4; r++) {
        int n = ty + r * 8;
        float w = tile[tx][n];
        u16 hi = f2bf(w);
        dhi[(size_t)(n0 + n) * K + k0 + tx] = hi;
        dlo[(size_t)(n0 + n) * K + k0 + tx] = f2bf(w - bf2f(hi));
      }
    }
    for (int idx = bid * 256 + tid; idx < NTOK * DM; idx += NB * 256) {
      int t = idx >> 9, d = idx & 511, ss = t & 127;
      a.xe[idx] = a.tok[(size_t)a.x[t] * DM + d] + a.pos[ss * DM + d];
      a.hbuf0[idx] = 0.0f;
      a.hbuf1[idx] = 0.0f;
    }
    const int nstat = 41 * 8 * 256;
    for (int idx = bid * 256 + tid; idx < nstat; idx += NB * 256)
      a.ln1sum[idx] = 0.0f;
  }
  cbar(a.bar + 256, NB, tid);

  unsigned* gctr = a.bar + grp * 32;
  unsigned tgt = 0;
  const size_t r512  = (size_t)grp * 128 * 512;
  const size_t r1024 = (size_t)grp * 128 * 1024;
  float* xe_g = a.xe + r512;
  u16 *ffh_g = a.ffh + r1024, *ffl_g = a.ffl + r1024;
  float* hb[2] = { a.hbuf0 + r512, a.hbuf1 + r512 };

  for (int it = 0; it < 40; it++) {
    const int l = it & 1;
    float* hR   = hb[it & 1];          // read (h)
    float* hAcc = hb[(it + 1) & 1];    // accum (seeded with h)
    float* ln1it = a.ln1sum + ((size_t)it * 8 + grp) * 256;
    float* ln1nx = a.ln1sum + ((size_t)(it + 1) * 8 + grp) * 256;

    // A: LN1 + QKV + attention + O·Wo partial into hAcc
    if (gb < 8) phaseA2(a, l, gb, grp, ln1it, hR, hAcc, smem, tid);
    tgt += 32; cbar(gctr, tgt, tid);

    // C: LN2(local stats) + FFN1 + ReLU (32 tiles)
    phaseC(a, l, hAcc, ffh_g, ffl_g, (gb >> 4) * 64, (gb & 15) * 64, smem, tid);
    tgt += 32; cbar(gctr, tgt, tid);

    // D: FFN2 + tanh-lerp; write next read+accum bufs; fold LN1 sums
    if (gb < 16)
      phaseD(a, l, ffh_g, ffl_g, hAcc, xe_g,
             hb[(it + 1) & 1], hb[it & 1], ln1nx,
             (gb >> 3) * 64, (gb & 7) * 64, smem, tid);
    tgt += 32; cbar(gctr, tgt, tid);
  }

  // group-local mean (final h in hb[0] == read buf of it=40)
  {
    float* hf = hb[0];
    const int dim = gb * 16 + (tid >> 4);
    const int sub = tid & 15;
    float sv = 0.f;
    for (int si = sub; si < 128; si += 16) sv += hf[(size_t)si * DM + dim];
    sv += __shfl_xor(sv, 1, 64); sv += __shfl_xor(sv, 2, 64);
    sv += __shfl_xor(sv, 4, 64); sv += __shfl_xor(sv, 8, 64);
    if (sub == 0) a.hm[grp * 512 + dim] = sv * (1.0f / 128.0f);
  }
  tgt += 32; cbar(gctr, tgt, tid);

  // group-local head
  {
    const int n = gb * 32 + (tid >> 3);
    const int sub = tid & 7;
    if (n < 1000) {
      const float* hr = a.hm + grp * 512 + sub * 64;
      const float* wr = a.hw + (size_t)(sub * 64) * 1000 + n;
      float sv = 0.f;
      for (int j = 0; j < 64; j++) sv = fmaf(hr[j], wr[(size_t)j * 1000], sv);
      sv += __shfl_xor(sv, 1, 64);
      sv += __shfl_xor(sv, 2, 64);
      sv += __shfl_xor(sv, 4, 64);
      if (sub == 0) a.out[grp * 1000 + n] = sv + a.hb[n];
    }
  }
}

// ---------------------------------------------------------------------------
extern "C" void kernel_launch(void* const* d_in, const int* in_sizes, int n_in,
                              void* d_out, int out_size, void* d_ws, size_t ws_size,
                              hipStream_t stream)
{
  (void)in_sizes; (void)n_in; (void)out_size; (void)ws_size;
  KArgs a;
  a.x    = (const int*)d_in[0];
  a.tok  = (const float*)d_in[2];
  a.pos  = (const float*)d_in[3];
  a.W[0] = (const float*)d_in[4];   a.bias6[0] = (const float*)d_in[5];
  a.W[1] = (const float*)d_in[6];   a.bias6[1] = (const float*)d_in[7];
  a.W[2] = (const float*)d_in[8];   a.bias6[2] = (const float*)d_in[9];
  a.W[3] = (const float*)d_in[10];  a.bias6[3] = (const float*)d_in[11];
  a.W[4] = (const float*)d_in[12];  a.bias6[4] = (const float*)d_in[13];
  a.W[5] = (const float*)d_in[14];  a.bias6[5] = (const float*)d_in[15];
  a.ln1g = (const float*)d_in[16];
  a.ln1b = (const float*)d_in[17];
  a.ln2g = (const float*)d_in[18];
  a.ln2b = (const float*)d_in[19];
  a.hw   = (const float*)d_in[20];
  a.hb   = (const float*)d_in[21];
  a.out  = (float*)d_out;

  char* ws = (char*)d_ws;
  const size_t MB = 1ull << 20;
  a.xe    = (float*)(ws + 0 * MB);
  a.hbuf0 = (float*)(ws + 2 * MB);
  a.hbuf1 = (float*)(ws + 4 * MB);
  a.ffh   = (u16*)(ws + 6 * MB);
  a.ffl   = (u16*)(ws + 8 * MB);
  a.hm    = (float*)(ws + 10 * MB);
  a.vT    = (u16*)(ws + 11 * MB);
  a.WTh[0] = (u16*)(ws + 12 * MB);  a.WTl[0] = (u16*)(ws + 13 * MB);
  a.WTh[1] = (u16*)(ws + 14 * MB);  a.WTl[1] = (u16*)(ws + 15 * MB);
  a.WTh[2] = (u16*)(ws + 16 * MB);  a.WTl[2] = (u16*)(ws + 17 * MB);
  a.WTh[3] = (u16*)(ws + 18 * MB);  a.WTl[3] = (u16*)(ws + 19 * MB);
  a.WTh[4] = (u16*)(ws + 20 * MB);  a.WTl[4] = (u16*)(ws + 22 * MB);
  a.WTh[5] = (u16*)(ws + 24 * MB);  a.WTl[5] = (u16*)(ws + 26 * MB);
  a.bar    = (unsigned*)(ws + 28 * MB);
  a.ln1sum = (float*)(ws + 29 * MB);

  bar_init<<<1, 256, 0, stream>>>(a.bar);
  persist<<<NB, 256, 0, stream>>>(a);
}

// Round 11
// 6368.096 us; speedup vs baseline: 1.1360x; 1.1360x over previous
//
#include <hip/hip_runtime.h>
#include <hip/hip_bf16.h>
#include <math.h>

// B=8, S=128; D=512; H=8, HD=64; L=2; steps=20 (fixed).
// 8 groups (=batches) x 16 blocks (128 total), 4 phases / 4 barriers per iter:
//   A: LN1+QKV+MFMA attention (8 blocks/group, 1/head)  -> obh/obl
//   B: O-proj + residual -> h', fold LN2 sums           (16 blocks, 1 tile)
//   C: LN2(atomic stats)+FFN1+ReLU                      (16 blocks, 2 tiles)
//   D: FFN2 + tanh-lerp in-place h, fold LN1 sums       (16 blocks, 1 tile)
// All K-loops: double-buffered global_load_lds (XOR swizzle) + reg A-prefetch.
#define NTOK 1024
#define DM   512
#define NB   128

typedef unsigned short u16;
typedef __attribute__((ext_vector_type(8))) short short8;
typedef __attribute__((ext_vector_type(4))) float f32x4;
typedef __attribute__((address_space(1))) const void* as1cv;
typedef __attribute__((address_space(3))) void* as3v;

__device__ inline u16 f2bf(float f) {
  __hip_bfloat16 h = __float2bfloat16(f);
  return *reinterpret_cast<u16*>(&h);
}
__device__ inline float bf2f(u16 b) {
  union { unsigned u; float f; } x; x.u = (unsigned)b << 16; return x.f;
}
__device__ inline void split8(const float* v, short8& hi, short8& lo) {
#pragma unroll
  for (int j = 0; j < 8; j++) {
    u16 h = f2bf(v[j]);
    hi[j] = (short)h;
    lo[j] = (short)f2bf(v[j] - bf2f(h));
  }
}
__device__ __forceinline__ f32x4 MFMA(short8 a, short8 b, f32x4 c) {
  return __builtin_amdgcn_mfma_f32_16x16x32_bf16(a, b, c, 0, 0, 0);
}
__device__ __forceinline__ void atomAddF(float* p, float v) {
  __hip_atomic_fetch_add(p, v, __ATOMIC_RELAXED, __HIP_MEMORY_SCOPE_AGENT);
}

enum { EP_RESID = 1, EP_TANHLERP = 3 };

struct KArgs {
  const int* x;
  const float* tok; const float* pos;
  const float* W[6];
  const float* bias6[6];
  const float* ln1g; const float* ln1b; const float* ln2g; const float* ln2b;
  const float* hw; const float* hb;
  float* out;
  float* xe; float* h;
  u16* obh; u16* obl;
  u16* ffh; u16* ffl;
  u16* vT;                      // [8 grp][8 head][64 dim][128 key] bf16
  float* hm;
  u16* WTh[6]; u16* WTl[6];     // split-bf16 transposed weights [L,N,K]
  float* ln1sum;                // [41][8][128][2] then ln2sum [40][8][128][2]
  float* ln2sum;
  unsigned* bar;
};

#define SMEM_BYTES 49152

__device__ __forceinline__ void cbar(unsigned* ctr, unsigned target, int tid) {
  __syncthreads();
  if (tid == 0) {
    __hip_atomic_fetch_add(ctr, 1u, __ATOMIC_RELEASE, __HIP_MEMORY_SCOPE_AGENT);
    while (__hip_atomic_load(ctr, __ATOMIC_RELAXED, __HIP_MEMORY_SCOPE_AGENT) < target)
      __builtin_amdgcn_s_sleep(2);
    __builtin_amdgcn_fence(__ATOMIC_ACQUIRE, "agent");
  }
  __syncthreads();
}
__global__ void bar_init(unsigned* bar) { bar[threadIdx.x] = 0u; bar[256 + threadIdx.x] = 0u; }

// ---------------- DMA helpers (XOR swizzle; verified r9) ----------------
__device__ __forceinline__ void dmaW64(const u16* gbase, int K, int k0, u16* lds, int tid) {
  const int wave = tid >> 6, lane = tid & 63;
#pragma unroll
  for (int i = 0; i < 2; i++) {
    const int lc = wave * 128 + i * 64 + lane;
    const int n = lc >> 3, sl = lc & 7;
    const int c = sl ^ (n & 7);
    const u16* g = gbase + (size_t)n * K + k0 + c * 8;
    u16* dst = lds + (size_t)(wave * 128 + i * 64) * 8;
    __builtin_amdgcn_global_load_lds((as1cv)(const void*)g, (as3v)(void*)dst, 16, 0, 0);
  }
}
__device__ __forceinline__ int boff64(int n, int cp) { return n * 64 + ((cp ^ (n & 7)) << 3); }

__device__ __forceinline__ void dmaW32(const u16* gbase, int K, int k0, u16* lds, int tid) {
  const int wave = tid >> 6, lane = tid & 63;
  const int lc = wave * 64 + lane;
  const int p = lc >> 3, s3 = lc & 7;
  const int c3 = s3 ^ (p & 7);
  const int n = p * 2 + (c3 >> 2);
  const int c = c3 & 3;
  const u16* g = gbase + (size_t)n * K + k0 + c * 8;
  u16* dst = lds + (size_t)(wave * 64) * 8;
  __builtin_amdgcn_global_load_lds((as1cv)(const void*)g, (as3v)(void*)dst, 16, 0, 0);
}
__device__ __forceinline__ int boff32(int n, int cq) {
  const int c3 = ((n & 1) << 2) | cq;
  return ((n >> 1) << 6) + ((c3 ^ ((n >> 1) & 7)) << 3);
}

// ---------------------------------------------------------------------------
// Phase A: per (batch,head). LN1 (atomic stats) fused into QKV A-frags, dbuf
// DMA weights; Q,K -> LDS bf16; V -> global vT; MFMA scores/softmax/PV; ob out.
// ---------------------------------------------------------------------------
__device__ void phaseA(const KArgs& a, int l, int head, int grp, const float* ln1,
                       const float* hR, u16* obh_g, u16* obl_g, char* sm, int tid)
{
  const int wave = tid >> 6, lane = tid & 63;
  const int q = lane >> 4, r16 = lane & 15;
  const int wm = (wave >> 1) * 32, wn = (wave & 1) * 32;
  const size_t wOff = (size_t)l * 512 * 512;
  const size_t hOff = (size_t)head * 64 * 512;

  const float* lg = a.ln1g + l * 512;
  const float* lb = a.ln1b + l * 512;
  const u16* wz[6] = { a.WTh[0] + wOff + hOff, a.WTl[0] + wOff + hOff,
                       a.WTh[1] + wOff + hOff, a.WTl[1] + wOff + hOff,
                       a.WTh[2] + wOff + hOff, a.WTl[2] + wOff + hOff };
  u16* vT = a.vT + (size_t)(grp * 8 + head) * 64 * 128;
  u16* Bst = (u16*)sm;     // [2 dbuf][6 tensors][2048 u16] = 49152 B

  int RB[4];
#pragma unroll
  for (int fi = 0; fi < 4; fi++) RB[fi] = (fi >> 1) * 64 + wm + (fi & 1) * 16;

  float mu[4], iv[4];
#pragma unroll
  for (int fi = 0; fi < 4; fi++) {
    const int row = RB[fi] + r16;
    const float sv = ln1[row * 2], sq = ln1[row * 2 + 1];
    const float m = sv * (1.0f / 512.0f);
    mu[fi] = m;
    iv[fi] = rsqrtf(sq * (1.0f / 512.0f) - m * m + 1e-5f);
  }

  f32x4 aq[4][2] = {}, ak[4][2] = {}, av[4][2] = {};

  float4 rA[4][2], rB4[4][2], rg[2], rb[2], rg2[2], rb2[2];
#pragma unroll
  for (int fi = 0; fi < 4; fi++) {
    const float* hp = hR + (size_t)(RB[fi] + r16) * DM + q * 8;
    rA[fi][0] = *(const float4*)hp; rA[fi][1] = *(const float4*)(hp + 4);
  }
  rg[0] = *(const float4*)&lg[q * 8]; rg[1] = *(const float4*)&lg[q * 8 + 4];
  rb[0] = *(const float4*)&lb[q * 8]; rb[1] = *(const float4*)&lb[q * 8 + 4];
#pragma unroll
  for (int z2 = 0; z2 < 6; z2++) dmaW32(wz[z2], 512, 0, Bst + z2 * 2048, tid);

  for (int ks = 0; ks < 16; ks++) {
    __syncthreads();                       // slab ks resident
    const int cur = (ks & 1) * 6 * 2048;
    if (ks + 1 < 16) {
      const int nxt = ((ks + 1) & 1) * 6 * 2048;
#pragma unroll
      for (int z2 = 0; z2 < 6; z2++) dmaW32(wz[z2], 512, (ks + 1) * 32, Bst + nxt + z2 * 2048, tid);
      const int kb = (ks + 1) * 32 + q * 8;
#pragma unroll
      for (int fi = 0; fi < 4; fi++) {
        const float* hp = hR + (size_t)(RB[fi] + r16) * DM + kb;
        rB4[fi][0] = *(const float4*)hp; rB4[fi][1] = *(const float4*)(hp + 4);
      }
      rg2[0] = *(const float4*)&lg[kb]; rg2[1] = *(const float4*)&lg[kb + 4];
      rb2[0] = *(const float4*)&lb[kb]; rb2[1] = *(const float4*)&lb[kb + 4];
    }
    short8 ah[4], al[4];
#pragma unroll
    for (int fi = 0; fi < 4; fi++) {
      float v[8] = {
        (rA[fi][0].x - mu[fi]) * iv[fi] * rg[0].x + rb[0].x,
        (rA[fi][0].y - mu[fi]) * iv[fi] * rg[0].y + rb[0].y,
        (rA[fi][0].z - mu[fi]) * iv[fi] * rg[0].z + rb[0].z,
        (rA[fi][0].w - mu[fi]) * iv[fi] * rg[0].w + rb[0].w,
        (rA[fi][1].x - mu[fi]) * iv[fi] * rg[1].x + rb[1].x,
        (rA[fi][1].y - mu[fi]) * iv[fi] * rg[1].y + rb[1].y,
        (rA[fi][1].z - mu[fi]) * iv[fi] * rg[1].z + rb[1].z,
        (rA[fi][1].w - mu[fi]) * iv[fi] * rg[1].w + rb[1].w };
      split8(v, ah[fi], al[fi]);
    }
#pragma unroll
    for (int z = 0; z < 3; z++) {
      f32x4 (*ac)[2] = (z == 0) ? aq : ((z == 1) ? ak : av);
#pragma unroll
      for (int fj = 0; fj < 2; fj++) {
        const int n = wn + fj * 16 + r16;
        const int off = boff32(n, q);
        short8 bh = *(const short8*)&Bst[cur + (z * 2) * 2048 + off];
        short8 bl = *(const short8*)&Bst[cur + (z * 2 + 1) * 2048 + off];
#pragma unroll
        for (int fi = 0; fi < 4; fi++) {
          ac[fi][fj] = MFMA(ah[fi], bh, ac[fi][fj]);
          ac[fi][fj] = MFMA(ah[fi], bl, ac[fi][fj]);
          ac[fi][fj] = MFMA(al[fi], bh, ac[fi][fj]);
        }
      }
    }
#pragma unroll
    for (int fi = 0; fi < 4; fi++) { rA[fi][0] = rB4[fi][0]; rA[fi][1] = rB4[fi][1]; }
    rg[0] = rg2[0]; rg[1] = rg2[1]; rb[0] = rb2[0]; rb[1] = rb2[1];
  }
  __syncthreads();   // Bst arena free

  u16 (*Qb)[66] = (u16(*)[66])sm;
  u16 (*Kb)[66] = (u16(*)[66])(sm + 16896);
  {
    const float* bq = a.bias6[0] + l * 512 + head * 64;
    const float* bk = a.bias6[1] + l * 512 + head * 64;
    const float* bv = a.bias6[2] + l * 512 + head * 64;
#pragma unroll
    for (int fi = 0; fi < 4; fi++) {
#pragma unroll
      for (int fj = 0; fj < 2; fj++) {
        const int col = wn + fj * 16 + r16;
        const int row0 = RB[fi] + q * 4;
        const float bqv = bq[col], bkv = bk[col], bvv = bv[col];
#pragma unroll
        for (int i = 0; i < 4; i++) {
          Qb[row0 + i][col] = f2bf(aq[fi][fj][i] + bqv);
          Kb[row0 + i][col] = f2bf(ak[fi][fj][i] + bkv);
          vT[(size_t)col * 128 + row0 + i] = f2bf(av[fi][fj][i] + bvv);
        }
      }
    }
  }
  __syncthreads();

  const int m0 = wave * 32;
  f32x4 sc[2][8] = {};
#pragma unroll
  for (int kk = 0; kk < 2; kk++) {
    short8 aQ[2];
#pragma unroll
    for (int fi = 0; fi < 2; fi++)
      aQ[fi] = *(const short8*)&Qb[m0 + fi * 16 + r16][kk * 32 + q * 8];
#pragma unroll
    for (int nt = 0; nt < 8; nt++) {
      short8 bK = *(const short8*)&Kb[nt * 16 + r16][kk * 32 + q * 8];
#pragma unroll
      for (int fi = 0; fi < 2; fi++) sc[fi][nt] = MFMA(aQ[fi], bK, sc[fi][nt]);
    }
  }
  __syncthreads();   // Pb overlays Qb/Kb

#pragma unroll
  for (int fi = 0; fi < 2; fi++) {
#pragma unroll
    for (int i = 0; i < 4; i++) {
      float mrow = -1e30f;
#pragma unroll
      for (int nt = 0; nt < 8; nt++) {
        float v = sc[fi][nt][i] * 0.125f; sc[fi][nt][i] = v; mrow = fmaxf(mrow, v);
      }
#pragma unroll
      for (int o = 1; o < 16; o <<= 1) mrow = fmaxf(mrow, __shfl_xor(mrow, o, 64));
      float lsum = 0.f;
#pragma unroll
      for (int nt = 0; nt < 8; nt++) {
        float p = __expf(sc[fi][nt][i] - mrow); sc[fi][nt][i] = p; lsum += p;
      }
#pragma unroll
      for (int o = 1; o < 16; o <<= 1) lsum += __shfl_xor(lsum, o, 64);
      const float inv = 1.0f / lsum;
#pragma unroll
      for (int nt = 0; nt < 8; nt++) sc[fi][nt][i] *= inv;
    }
  }
  u16 (*Pb)[132] = (u16(*)[132])sm;
#pragma unroll
  for (int fi = 0; fi < 2; fi++)
#pragma unroll
    for (int nt = 0; nt < 8; nt++)
#pragma unroll
      for (int i = 0; i < 4; i++)
        Pb[m0 + fi * 16 + q * 4 + i][nt * 16 + r16] = f2bf(sc[fi][nt][i]);
  __syncthreads();

  f32x4 oa[2][4] = {};
#pragma unroll
  for (int kt = 0; kt < 4; kt++) {
    short8 aP[2];
#pragma unroll
    for (int fi = 0; fi < 2; fi++)
      aP[fi] = *(const short8*)&Pb[m0 + fi * 16 + r16][kt * 32 + q * 8];
#pragma unroll
    for (int nt = 0; nt < 4; nt++) {
      short8 bV = *(const short8*)(vT + (size_t)(nt * 16 + r16) * 128 + kt * 32 + q * 8);
#pragma unroll
      for (int fi = 0; fi < 2; fi++) oa[fi][nt] = MFMA(aP[fi], bV, oa[fi][nt]);
    }
  }
#pragma unroll
  for (int fi = 0; fi < 2; fi++)
#pragma unroll
    for (int nt = 0; nt < 4; nt++)
#pragma unroll
      for (int i = 0; i < 4; i++) {
        const int row = m0 + fi * 16 + q * 4 + i;
        const int col = head * 64 + nt * 16 + r16;
        float v = oa[fi][nt][i];
        u16 hv = f2bf(v);
        obh_g[(size_t)row * DM + col] = hv;
        obl_g[(size_t)row * DM + col] = f2bf(v - bf2f(hv));
      }
}

// ---------------------------------------------------------------------------
// tileBD: 64x64 split-bf16x3 GEMM, A pre-split (bf16 hi/lo, K-contig), dbuf
// weight DMA. EP_RESID: h'=h+val, fold lnacc. EP_TANHLERP: h''=lerp, fold.
// ---------------------------------------------------------------------------
template<int EP>
__device__ void tileBD(const u16* Ahi, const u16* Alo, int K,
                       const u16* Whi, const u16* Wlo, const float* bias,
                       int bm, int bn, float* hIO, const float* Xx,
                       float* lnacc, char* sm, int tid)
{
  u16* Bsh = (u16*)sm;                 // [2][4096]
  u16* Bsl = (u16*)(sm + 16384);
  const int wave = tid >> 6, lane = tid & 63;
  const int q = lane >> 4, r16 = lane & 15;
  const int wm = (wave >> 1) * 32, wn = (wave & 1) * 32;

  const u16* bh0 = Whi + (size_t)bn * K;
  const u16* bl0 = Wlo + (size_t)bn * K;
  f32x4 acc[2][2] = {};
  const int nk = K >> 6;

  short8 pah[2][2], pal[2][2], nah[2][2], nal[2][2];
#pragma unroll
  for (int kk = 0; kk < 2; kk++)
#pragma unroll
    for (int fi = 0; fi < 2; fi++) {
      const size_t ao = (size_t)(bm + wm + fi * 16 + r16) * K + kk * 32 + q * 8;
      pah[kk][fi] = *(const short8*)(Ahi + ao);
      pal[kk][fi] = *(const short8*)(Alo + ao);
    }
  dmaW64(bh0, K, 0, Bsh, tid);
  dmaW64(bl0, K, 0, Bsl, tid);

  for (int ks = 0; ks < nk; ks++) {
    __syncthreads();
    const int cur = (ks & 1) * 4096;
    if (ks + 1 < nk) {
      const int nxt = ((ks + 1) & 1) * 4096;
      dmaW64(bh0, K, (ks + 1) * 64, Bsh + nxt, tid);
      dmaW64(bl0, K, (ks + 1) * 64, Bsl + nxt, tid);
#pragma unroll
      for (int kk = 0; kk < 2; kk++)
#pragma unroll
        for (int fi = 0; fi < 2; fi++) {
          const size_t ao = (size_t)(bm + wm + fi * 16 + r16) * K + (ks + 1) * 64 + kk * 32 + q * 8;
          nah[kk][fi] = *(const short8*)(Ahi + ao);
          nal[kk][fi] = *(const short8*)(Alo + ao);
        }
    }
#pragma unroll
    for (int kk = 0; kk < 2; kk++) {
#pragma unroll
      for (int fj = 0; fj < 2; fj++) {
        const int n = wn + fj * 16 + r16;
        const int off = boff64(n, kk * 4 + q);
        short8 bh = *(const short8*)&Bsh[cur + off];
        short8 bl = *(const short8*)&Bsl[cur + off];
#pragma unroll
        for (int fi = 0; fi < 2; fi++) {
          acc[fi][fj] = MFMA(pah[kk][fi], bh, acc[fi][fj]);
          acc[fi][fj] = MFMA(pah[kk][fi], bl, acc[fi][fj]);
          acc[fi][fj] = MFMA(pal[kk][fi], bh, acc[fi][fj]);
        }
      }
    }
#pragma unroll
    for (int kk = 0; kk < 2; kk++)
#pragma unroll
      for (int fi = 0; fi < 2; fi++) { pah[kk][fi] = nah[kk][fi]; pal[kk][fi] = nal[kk][fi]; }
  }

  float outv[2][2][4];
#pragma unroll
  for (int fi = 0; fi < 2; fi++)
#pragma unroll
    for (int fj = 0; fj < 2; fj++) {
      const int col = bn + wn + fj * 16 + r16;
      const float bvv = bias[col];
      const int row0 = bm + wm + fi * 16 + q * 4;
#pragma unroll
      for (int i = 0; i < 4; i++) {
        const size_t off = (size_t)(row0 + i) * DM + col;
        if (EP == EP_RESID) {
          float hv = hIO[off] + acc[fi][fj][i] + bvv;
          hIO[off] = hv; outv[fi][fj][i] = hv;
        } else {
          float hv = hIO[off];
          float hn = 0.5f * hv + 0.5f * tanhf(hv + acc[fi][fj][i] + bvv + Xx[off]);
          hIO[off] = hn; outv[fi][fj][i] = hn;
        }
      }
    }
#pragma unroll
  for (int fi = 0; fi < 2; fi++)
#pragma unroll
    for (int i = 0; i < 4; i++) {
      float a0 = outv[fi][0][i], a1 = outv[fi][1][i];
      float s1 = a0 + a1, s2 = a0 * a0 + a1 * a1;
#pragma unroll
      for (int o = 1; o < 16; o <<= 1) { s1 += __shfl_xor(s1, o, 64); s2 += __shfl_xor(s2, o, 64); }
      if (r16 == 0) {
        const int row = bm + wm + fi * 16 + q * 4 + i;
        atomAddF(&lnacc[row * 2], s1);
        atomAddF(&lnacc[row * 2 + 1], s2);
      }
    }
}

// ---------------------------------------------------------------------------
// tileC: LN2 (atomic stats) + FFN1 + ReLU, dbuf DMA, split bf16 out.
// ---------------------------------------------------------------------------
__device__ void tileC(const KArgs& a, int l, const float* h_g, const float* lnsrc,
                      u16* ffh_g, u16* ffl_g, int bm, int bn, char* sm, int tid)
{
  u16* Bsh = (u16*)sm;
  u16* Bsl = (u16*)(sm + 16384);
  const int wave = tid >> 6, lane = tid & 63;
  const int q = lane >> 4, r16 = lane & 15;
  const int wm = (wave >> 1) * 32, wn = (wave & 1) * 32;
  const size_t fOff = (size_t)l * 512 * 1024;
  const float* lg = a.ln2g + l * 512;
  const float* lb = a.ln2b + l * 512;

  float mu[2], iv[2];
#pragma unroll
  for (int fi = 0; fi < 2; fi++) {
    const int rr = bm + wm + fi * 16 + r16;
    const float sv = lnsrc[rr * 2], sq = lnsrc[rr * 2 + 1];
    const float m = sv * (1.0f / 512.0f);
    mu[fi] = m;
    iv[fi] = rsqrtf(sq * (1.0f / 512.0f) - m * m + 1e-5f);
  }

  const u16* bh0 = a.WTh[4] + fOff + (size_t)bn * 512;
  const u16* bl0 = a.WTl[4] + fOff + (size_t)bn * 512;
  f32x4 acc[2][2] = {};

  float4 rA[2][2][2], rB4[2][2][2], rg[2][2], rb[2][2], rg2[2][2], rb2[2][2];
#pragma unroll
  for (int kk = 0; kk < 2; kk++) {
    const int kb = kk * 32 + q * 8;
#pragma unroll
    for (int fi = 0; fi < 2; fi++) {
      const float* hp = h_g + (size_t)(bm + wm + fi * 16 + r16) * DM + kb;
      rA[kk][fi][0] = *(const float4*)hp; rA[kk][fi][1] = *(const float4*)(hp + 4);
    }
    rg[kk][0] = *(const float4*)&lg[kb]; rg[kk][1] = *(const float4*)&lg[kb + 4];
    rb[kk][0] = *(const float4*)&lb[kb]; rb[kk][1] = *(const float4*)&lb[kb + 4];
  }
  dmaW64(bh0, 512, 0, Bsh, tid);
  dmaW64(bl0, 512, 0, Bsl, tid);

  for (int ks = 0; ks < 8; ks++) {
    __syncthreads();
    const int cur = (ks & 1) * 4096;
    if (ks + 1 < 8) {
      const int nxt = ((ks + 1) & 1) * 4096;
      dmaW64(bh0, 512, (ks + 1) * 64, Bsh + nxt, tid);
      dmaW64(bl0, 512, (ks + 1) * 64, Bsl + nxt, tid);
#pragma unroll
      for (int kk = 0; kk < 2; kk++) {
        const int kb = (ks + 1) * 64 + kk * 32 + q * 8;
#pragma unroll
        for (int fi = 0; fi < 2; fi++) {
          const float* hp = h_g + (size_t)(bm + wm + fi * 16 + r16) * DM + kb;
          rB4[kk][fi][0] = *(const float4*)hp; rB4[kk][fi][1] = *(const float4*)(hp + 4);
        }
        rg2[kk][0] = *(const float4*)&lg[kb]; rg2[kk][1] = *(const float4*)&lg[kb + 4];
        rb2[kk][0] = *(const float4*)&lb[kb]; rb2[kk][1] = *(const float4*)&lb[kb + 4];
      }
    }
#pragma unroll
    for (int kk = 0; kk < 2; kk++) {
      short8 ah[2], al[2];
#pragma unroll
      for (int fi = 0; fi < 2; fi++) {
        float v[8] = {
          (rA[kk][fi][0].x - mu[fi]) * iv[fi] * rg[kk][0].x + rb[kk][0].x,
          (rA[kk][fi][0].y - mu[fi]) * iv[fi] * rg[kk][0].y + rb[kk][0].y,
          (rA[kk][fi][0].z - mu[fi]) * iv[fi] * rg[kk][0].z + rb[kk][0].z,
          (rA[kk][fi][0].w - mu[fi]) * iv[fi] * rg[kk][0].w + rb[kk][0].w,
          (rA[kk][fi][1].x - mu[fi]) * iv[fi] * rg[kk][1].x + rb[kk][1].x,
          (rA[kk][fi][1].y - mu[fi]) * iv[fi] * rg[kk][1].y + rb[kk][1].y,
          (rA[kk][fi][1].z - mu[fi]) * iv[fi] * rg[kk][1].z + rb[kk][1].z,
          (rA[kk][fi][1].w - mu[fi]) * iv[fi] * rg[kk][1].w + rb[kk][1].w };
        split8(v, ah[fi], al[fi]);
      }
#pragma unroll
      for (int fj = 0; fj < 2; fj++) {
        const int n = wn + fj * 16 + r16;
        const int off = boff64(n, kk * 4 + q);
        short8 bh = *(const short8*)&Bsh[cur + off];
        short8 bl = *(const short8*)&Bsl[cur + off];
#pragma unroll
        for (int fi = 0; fi < 2; fi++) {
          acc[fi][fj] = MFMA(ah[fi], bh, acc[fi][fj]);
          acc[fi][fj] = MFMA(ah[fi], bl, acc[fi][fj]);
          acc[fi][fj] = MFMA(al[fi], bh, acc[fi][fj]);
        }
      }
    }
#pragma unroll
    for (int kk = 0; kk < 2; kk++) {
#pragma unroll
      for (int fi = 0; fi < 2; fi++) { rA[kk][fi][0] = rB4[kk][fi][0]; rA[kk][fi][1] = rB4[kk][fi][1]; }
      rg[kk][0] = rg2[kk][0]; rg[kk][1] = rg2[kk][1];
      rb[kk][0] = rb2[kk][0]; rb[kk][1] = rb2[kk][1];
    }
  }

  const float* b1 = a.bias6[4] + l * 1024;
#pragma unroll
  for (int fi = 0; fi < 2; fi++)
#pragma unroll
    for (int fj = 0; fj < 2; fj++) {
      const int col = bn + wn + fj * 16 + r16;
      const float bvv = b1[col];
      const int row0 = bm + wm + fi * 16 + q * 4;
#pragma unroll
      for (int i = 0; i < 4; i++) {
        const size_t off = (size_t)(row0 + i) * 1024 + col;
        float r = fmaxf(acc[fi][fj][i] + bvv, 0.f);
        u16 hv = f2bf(r);
        ffh_g[off] = hv; ffl_g[off] = f2bf(r - bf2f(hv));
      }
    }
}

// ---------------------------------------------------------------------------
__global__ __launch_bounds__(256, 1) void persist(KArgs a)
{
  __shared__ __align__(16) char smem[SMEM_BYTES];
  const int tid = threadIdx.x;
  const int bid = blockIdx.x;
  const int grp = bid & 7;     // batch (XCD-local under %8 dispatch — perf only)
  const int gb  = bid >> 3;    // 0..15 within group

  // ---- phase 0: weight split-transpose + embed + zero h + LN sums ----
  {
    float (*tile)[33] = (float (*)[33])smem;
    const int tx = tid & 31, ty = tid >> 5;
    for (int t = bid; t < 4096; t += NB) {
      int tensor, z, k0, n0, K, N;
      if (t < 2048)      { tensor = t >> 9;  int rem = t & 511;  z = rem >> 8; int r2 = rem & 255;
                           K = 512;  N = 512;  k0 = (r2 >> 4) << 5; n0 = (r2 & 15) << 5; }
      else if (t < 3072) { tensor = 4;       int rem = t - 2048; z = rem >> 9; int r2 = rem & 511;
                           K = 512;  N = 1024; k0 = (r2 >> 5) << 5; n0 = (r2 & 31) << 5; }
      else               { tensor = 5;       int rem = t - 3072; z = rem >> 9; int r2 = rem & 511;
                           K = 1024; N = 512;  k0 = (r2 >> 4) << 5; n0 = (r2 & 15) << 5; }
      const float* src = a.W[tensor]   + (size_t)z * K * N;
      u16* dhi         = a.WTh[tensor] + (size_t)z * K * N;
      u16* dlo         = a.WTl[tensor] + (size_t)z * K * N;
      __syncthreads();
#pragma unroll
      for (int r = 0; r < 4; r++) {
        int k = ty + r * 8;
        tile[k][tx] = src[(size_t)(k0 + k) * N + n0 + tx];
      }
      __syncthreads();
#pragma unroll
      for (int r = 0; r < 4; r++) {
        int n = ty + r * 8;
        float w = tile[tx][n];
        u16 hi = f2bf(w);
        dhi[(size_t)(n0 + n) * K + k0 + tx] = hi;
        dlo[(size_t)(n0 + n) * K + k0 + tx] = f2bf(w - bf2f(hi));
      }
    }
    for (int idx = bid * 256 + tid; idx < NTOK * DM; idx += NB * 256) {
      int t = idx >> 9, d = idx & 511, ss = t & 127;
      a.xe[idx] = a.tok[(size_t)a.x[t] * DM + d] + a.pos[ss * DM + d];
      a.h[idx] = 0.0f;
    }
    const int nstat = (41 + 40) * 8 * 256;
    for (int idx = bid * 256 + tid; idx < nstat; idx += NB * 256)
      a.ln1sum[idx] = 0.0f;
  }
  cbar(a.bar + 256, NB, tid);

  unsigned* gctr = a.bar + grp * 32;
  unsigned tgt = 0;
  const size_t r512  = (size_t)grp * 128 * 512;
  const size_t r1024 = (size_t)grp * 128 * 1024;
  float* h_g  = a.h  + r512;
  float* xe_g = a.xe + r512;
  u16 *obh_g = a.obh + r512, *obl_g = a.obl + r512;
  u16 *ffh_g = a.ffh + r1024, *ffl_g = a.ffl + r1024;

  for (int it = 0; it < 40; it++) {
    const int l = it & 1;
    const size_t wOff = (size_t)l * 512 * 512;
    const size_t fOff = (size_t)l * 512 * 1024;
    float* ln1it = a.ln1sum + ((size_t)it * 8 + grp) * 256;
    float* ln2it = a.ln2sum + ((size_t)it * 8 + grp) * 256;
    float* ln1nx = a.ln1sum + ((size_t)(it + 1) * 8 + grp) * 256;

    // A: LN1 + QKV + attention (8 blocks, 1/head)
    if (gb < 8) phaseA(a, l, gb, grp, ln1it, h_g, obh_g, obl_g, smem, tid);
    tgt += 16; cbar(gctr, tgt, tid);

    // B: O-proj + residual -> h', fold LN2 (16 tiles, 1 each)
    tileBD<EP_RESID>(obh_g, obl_g, 512, a.WTh[3] + wOff, a.WTl[3] + wOff,
                     a.bias6[3] + l * 512, (gb >> 3) * 64, (gb & 7) * 64,
                     h_g, nullptr, ln2it, smem, tid);
    tgt += 16; cbar(gctr, tgt, tid);

    // C: LN2 + FFN1 + ReLU (32 tiles, 2 each)
    for (int t = 0; t < 2; t++)
      tileC(a, l, h_g, ln2it, ffh_g, ffl_g,
            (gb >> 3) * 64, (gb & 7) * 64 + t * 512, smem, tid);
    tgt += 16; cbar(gctr, tgt, tid);

    // D: FFN2 + tanh-lerp in place, fold next LN1 (16 tiles, 1 each)
    tileBD<EP_TANHLERP>(ffh_g, ffl_g, 1024, a.WTh[5] + fOff, a.WTl[5] + fOff,
                        a.bias6[5] + l * 512, (gb >> 3) * 64, (gb & 7) * 64,
                        h_g, xe_g, ln1nx, smem, tid);
    tgt += 16; cbar(gctr, tgt, tid);
  }

  // group-local mean: hm[grp][512]; 32 dims/block, 8 lanes each
  {
    const int dim = gb * 32 + (tid >> 3);
    const int sub = tid & 7;
    float sv = 0.f;
    for (int si = sub; si < 128; si += 8) sv += h_g[(size_t)si * DM + dim];
    sv += __shfl_xor(sv, 1, 64); sv += __shfl_xor(sv, 2, 64); sv += __shfl_xor(sv, 4, 64);
    if (sub == 0) a.hm[grp * 512 + dim] = sv * (1.0f / 128.0f);
  }
  tgt += 16; cbar(gctr, tgt, tid);

  // group-local head: out[grp][1000]; 63 outputs/block, 4 lanes each
  {
    const int idx = tid >> 2;
    const int n = gb * 63 + idx;
    const int sub = tid & 3;
    if (idx < 63 && n < 1000) {
      const float* hr = a.hm + grp * 512 + sub * 128;
      const float* wr = a.hw + (size_t)(sub * 128) * 1000 + n;
      float sv = 0.f;
      for (int j = 0; j < 128; j++) sv = fmaf(hr[j], wr[(size_t)j * 1000], sv);
      sv += __shfl_xor(sv, 1, 64);
      sv += __shfl_xor(sv, 2, 64);
      if (sub == 0) a.out[grp * 1000 + n] = sv + a.hb[n];
    }
    // n = 1008..1015 never assigned; gb*63 covers 0..1007 >= 1000 ✓
  }
}

// ---------------------------------------------------------------------------
extern "C" void kernel_launch(void* const* d_in, const int* in_sizes, int n_in,
                              void* d_out, int out_size, void* d_ws, size_t ws_size,
                              hipStream_t stream)
{
  (void)in_sizes; (void)n_in; (void)out_size; (void)ws_size;
  KArgs a;
  a.x    = (const int*)d_in[0];
  a.tok  = (const float*)d_in[2];
  a.pos  = (const float*)d_in[3];
  a.W[0] = (const float*)d_in[4];   a.bias6[0] = (const float*)d_in[5];
  a.W[1] = (const float*)d_in[6];   a.bias6[1] = (const float*)d_in[7];
  a.W[2] = (const float*)d_in[8];   a.bias6[2] = (const float*)d_in[9];
  a.W[3] = (const float*)d_in[10];  a.bias6[3] = (const float*)d_in[11];
  a.W[4] = (const float*)d_in[12];  a.bias6[4] = (const float*)d_in[13];
  a.W[5] = (const float*)d_in[14];  a.bias6[5] = (const float*)d_in[15];
  a.ln1g = (const float*)d_in[16];
  a.ln1b = (const float*)d_in[17];
  a.ln2g = (const float*)d_in[18];
  a.ln2b = (const float*)d_in[19];
  a.hw   = (const float*)d_in[20];
  a.hb   = (const float*)d_in[21];
  a.out  = (float*)d_out;

  char* ws = (char*)d_ws;
  const size_t MB = 1ull << 20;
  a.xe   = (float*)(ws + 0 * MB);
  a.h    = (float*)(ws + 2 * MB);
  a.obh  = (u16*)(ws + 4 * MB);
  a.obl  = (u16*)(ws + 5 * MB);
  a.ffh  = (u16*)(ws + 6 * MB);
  a.ffl  = (u16*)(ws + 8 * MB);
  a.hm   = (float*)(ws + 10 * MB);
  a.vT   = (u16*)(ws + 11 * MB);
  a.WTh[0] = (u16*)(ws + 12 * MB);  a.WTl[0] = (u16*)(ws + 13 * MB);
  a.WTh[1] = (u16*)(ws + 14 * MB);  a.WTl[1] = (u16*)(ws + 15 * MB);
  a.WTh[2] = (u16*)(ws + 16 * MB);  a.WTl[2] = (u16*)(ws + 17 * MB);
  a.WTh[3] = (u16*)(ws + 18 * MB);  a.WTl[3] = (u16*)(ws + 19 * MB);
  a.WTh[4] = (u16*)(ws + 20 * MB);  a.WTl[4] = (u16*)(ws + 22 * MB);
  a.WTh[5] = (u16*)(ws + 24 * MB);  a.WTl[5] = (u16*)(ws + 26 * MB);
  a.bar    = (unsigned*)(ws + 28 * MB);
  a.ln1sum = (float*)(ws + 29 * MB);
  a.ln2sum = a.ln1sum + (size_t)41 * 8 * 256;

  bar_init<<<1, 256, 0, stream>>>(a.bar);
  persist<<<NB, 256, 0, stream>>>(a);
}

// Round 12
// 5906.280 us; speedup vs baseline: 1.2249x; 1.0782x over previous
//
#include <hip/hip_runtime.h>
#include <hip/hip_bf16.h>
#include <math.h>

// B=8, S=128; D=512; H=8, HD=64; L=2; steps=20 (fixed).
// 8 groups (=batches) x 16 blocks. 4 phases/iter. K-loops pipelined with
// s_waitcnt vmcnt(N) + raw s_barrier (DMA stays in flight across barriers);
// B/C/D use a 3-deep LDS ring; first stages prefetched inside the group
// barrier (weights are read-only -> safe across the acquire invalidate).
#define NTOK 1024
#define DM   512
#define NB   128

typedef unsigned short u16;
typedef __attribute__((ext_vector_type(8))) short short8;
typedef __attribute__((ext_vector_type(4))) float f32x4;
typedef __attribute__((address_space(1))) const void* as1cv;
typedef __attribute__((address_space(3))) void* as3v;

// s_waitcnt imms (gfx9): vmcnt[3:0]|[15:14], expcnt=7<<4, lgkm=15<<8
#define VM12 0x0F7C
#define VM20 0x4F74
#define VM0  0x0F70

__device__ inline u16 f2bf(float f) {
  __hip_bfloat16 h = __float2bfloat16(f);
  return *reinterpret_cast<u16*>(&h);
}
__device__ inline float bf2f(u16 b) {
  union { unsigned u; float f; } x; x.u = (unsigned)b << 16; return x.f;
}
__device__ inline void split8(const float* v, short8& hi, short8& lo) {
#pragma unroll
  for (int j = 0; j < 8; j++) {
    u16 h = f2bf(v[j]);
    hi[j] = (short)h;
    lo[j] = (short)f2bf(v[j] - bf2f(h));
  }
}
__device__ __forceinline__ f32x4 MFMA(short8 a, short8 b, f32x4 c) {
  return __builtin_amdgcn_mfma_f32_16x16x32_bf16(a, b, c, 0, 0, 0);
}
__device__ __forceinline__ void atomAddF(float* p, float v) {
  __hip_atomic_fetch_add(p, v, __ATOMIC_RELAXED, __HIP_MEMORY_SCOPE_AGENT);
}

enum { EP_RESID = 1, EP_TANHLERP = 3 };

struct KArgs {
  const int* x;
  const float* tok; const float* pos;
  const float* W[6];
  const float* bias6[6];
  const float* ln1g; const float* ln1b; const float* ln2g; const float* ln2b;
  const float* hw; const float* hb;
  float* out;
  float* xe; float* h;
  u16* obh; u16* obl;
  u16* ffh; u16* ffl;
  u16* vT;
  float* hm;
  u16* WTh[6]; u16* WTl[6];
  float* ln1sum; float* ln2sum;
  unsigned* bar;
};

#define SMEM_BYTES 49152

// ---- split barrier: arrive (drain+release) / [prefetch] / wait (acquire) ----
__device__ __forceinline__ void bar_arrive(unsigned* ctr, int tid) {
  __syncthreads();     // all waves' stores drained before release
  if (tid == 0)
    __hip_atomic_fetch_add(ctr, 1u, __ATOMIC_RELEASE, __HIP_MEMORY_SCOPE_AGENT);
}
__device__ __forceinline__ void bar_wait(unsigned* ctr, unsigned target, int tid) {
  if (tid == 0) {
    while (__hip_atomic_load(ctr, __ATOMIC_RELAXED, __HIP_MEMORY_SCOPE_AGENT) < target)
      __builtin_amdgcn_s_sleep(2);
    __builtin_amdgcn_fence(__ATOMIC_ACQUIRE, "agent");
  }
  __syncthreads();     // also drains this block's prefetch DMAs
}
__global__ void bar_init(unsigned* bar) { bar[threadIdx.x] = 0u; bar[256 + threadIdx.x] = 0u; }

// ---------------- DMA helpers (XOR swizzle; verified r9) ----------------
__device__ __forceinline__ void dmaW64(const u16* gbase, int K, int k0, u16* lds, int tid) {
  const int wave = tid >> 6, lane = tid & 63;
#pragma unroll
  for (int i = 0; i < 2; i++) {
    const int lc = wave * 128 + i * 64 + lane;
    const int n = lc >> 3, sl = lc & 7;
    const int c = sl ^ (n & 7);
    const u16* g = gbase + (size_t)n * K + k0 + c * 8;
    u16* dst = lds + (size_t)(wave * 128 + i * 64) * 8;
    __builtin_amdgcn_global_load_lds((as1cv)(const void*)g, (as3v)(void*)dst, 16, 0, 0);
  }
}
__device__ __forceinline__ int boff64(int n, int cp) { return n * 64 + ((cp ^ (n & 7)) << 3); }

__device__ __forceinline__ void dmaW32(const u16* gbase, int K, int k0, u16* lds, int tid) {
  const int wave = tid >> 6, lane = tid & 63;
  const int lc = wave * 64 + lane;
  const int p = lc >> 3, s3 = lc & 7;
  const int c3 = s3 ^ (p & 7);
  const int n = p * 2 + (c3 >> 2);
  const int c = c3 & 3;
  const u16* g = gbase + (size_t)n * K + k0 + c * 8;
  u16* dst = lds + (size_t)(wave * 64) * 8;
  __builtin_amdgcn_global_load_lds((as1cv)(const void*)g, (as3v)(void*)dst, 16, 0, 0);
}
__device__ __forceinline__ int boff32(int n, int cq) {
  const int c3 = ((n & 1) << 2) | cq;
  return ((n >> 1) << 6) + ((c3 ^ ((n >> 1) & 7)) << 3);
}

// prefetches (issued between bar_arrive and bar_wait)
__device__ __forceinline__ void pfBD2(const u16* bh0, const u16* bl0, int K, char* sm, int tid) {
  dmaW64(bh0, K, 0,  (u16*)sm, tid);
  dmaW64(bl0, K, 0,  (u16*)sm + 4096, tid);
  dmaW64(bh0, K, 64, (u16*)(sm + 16384), tid);
  dmaW64(bl0, K, 64, (u16*)(sm + 16384) + 4096, tid);
}
__device__ __forceinline__ void pfA(const KArgs& a, int l, int head, char* sm, int tid) {
  const size_t o = (size_t)l * 512 * 512 + (size_t)head * 64 * 512;
  const u16* wz[6] = { a.WTh[0] + o, a.WTl[0] + o, a.WTh[1] + o,
                       a.WTl[1] + o, a.WTh[2] + o, a.WTl[2] + o };
#pragma unroll
  for (int z = 0; z < 6; z++) dmaW32(wz[z], 512, 0, (u16*)sm + z * 2048, tid);
}

// ---------------------------------------------------------------------------
// Phase A: per (batch,head). LN1(atomic stats) fused into QKV A-frags; dbuf-2
// weight DMA with vmcnt/s_barrier pipeline; Q,K->LDS; V->vT; MFMA attention.
// ---------------------------------------------------------------------------
__device__ void phaseA(const KArgs& a, int l, int head, int grp, const float* ln1,
                       const float* hR, u16* obh_g, u16* obl_g, char* sm, int tid)
{
  const int wave = tid >> 6, lane = tid & 63;
  const int q = lane >> 4, r16 = lane & 15;
  const int wm = (wave >> 1) * 32, wn = (wave & 1) * 32;
  const size_t wOff = (size_t)l * 512 * 512;
  const size_t hOff = (size_t)head * 64 * 512;

  const float* lg = a.ln1g + l * 512;
  const float* lb = a.ln1b + l * 512;
  const u16* wz[6] = { a.WTh[0] + wOff + hOff, a.WTl[0] + wOff + hOff,
                       a.WTh[1] + wOff + hOff, a.WTl[1] + wOff + hOff,
                       a.WTh[2] + wOff + hOff, a.WTl[2] + wOff + hOff };
  u16* vT = a.vT + (size_t)(grp * 8 + head) * 64 * 128;
  u16* buf[2] = { (u16*)sm, (u16*)sm + 12288 };   // 24576 B each

  int RB[4];
#pragma unroll
  for (int fi = 0; fi < 4; fi++) RB[fi] = (fi >> 1) * 64 + wm + (fi & 1) * 16;

  float mu[4], iv[4];
#pragma unroll
  for (int fi = 0; fi < 4; fi++) {
    const int row = RB[fi] + r16;
    const float sv = ln1[row * 2], sq = ln1[row * 2 + 1];
    const float m = sv * (1.0f / 512.0f);
    mu[fi] = m;
    iv[fi] = rsqrtf(sq * (1.0f / 512.0f) - m * m + 1e-5f);
  }

  f32x4 aq[4][2] = {}, ak[4][2] = {}, av[4][2] = {};

  float4 rA[4][2], rB4[4][2], rg[2], rb[2], rg2[2], rb2[2];
#pragma unroll
  for (int fi = 0; fi < 4; fi++) {
    const float* hp = hR + (size_t)(RB[fi] + r16) * DM + q * 8;
    rA[fi][0] = *(const float4*)hp; rA[fi][1] = *(const float4*)(hp + 4);
  }
  rg[0] = *(const float4*)&lg[q * 8]; rg[1] = *(const float4*)&lg[q * 8 + 4];
  rb[0] = *(const float4*)&lb[q * 8]; rb[1] = *(const float4*)&lb[q * 8 + 4];
  // stage 0 was prefetched inside the preceding barrier (pfA)

  for (int ks = 0; ks < 16; ks++) {
    if (ks + 1 < 16) {                  // A(ks+1): 12 vm-insts
      const int kb = (ks + 1) * 32 + q * 8;
#pragma unroll
      for (int fi = 0; fi < 4; fi++) {
        const float* hp = hR + (size_t)(RB[fi] + r16) * DM + kb;
        rB4[fi][0] = *(const float4*)hp; rB4[fi][1] = *(const float4*)(hp + 4);
      }
      rg2[0] = *(const float4*)&lg[kb]; rg2[1] = *(const float4*)&lg[kb + 4];
      rb2[0] = *(const float4*)&lb[kb]; rb2[1] = *(const float4*)&lb[kb + 4];
      __builtin_amdgcn_s_waitcnt(VM12);   // DMA(ks)+A(ks) done; A(ks+1) in flight
    } else {
      __builtin_amdgcn_s_waitcnt(VM0);
    }
    __builtin_amdgcn_s_barrier();
    if (ks + 1 < 16) {                  // DMA(ks+1) -> other buf (safe post-barrier)
      u16* nb = buf[(ks + 1) & 1];
#pragma unroll
      for (int z2 = 0; z2 < 6; z2++) dmaW32(wz[z2], 512, (ks + 1) * 32, nb + z2 * 2048, tid);
    }
    const u16* cb = buf[ks & 1];
    short8 ah[4], al[4];
#pragma unroll
    for (int fi = 0; fi < 4; fi++) {
      float v[8] = {
        (rA[fi][0].x - mu[fi]) * iv[fi] * rg[0].x + rb[0].x,
        (rA[fi][0].y - mu[fi]) * iv[fi] * rg[0].y + rb[0].y,
        (rA[fi][0].z - mu[fi]) * iv[fi] * rg[0].z + rb[0].z,
        (rA[fi][0].w - mu[fi]) * iv[fi] * rg[0].w + rb[0].w,
        (rA[fi][1].x - mu[fi]) * iv[fi] * rg[1].x + rb[1].x,
        (rA[fi][1].y - mu[fi]) * iv[fi] * rg[1].y + rb[1].y,
        (rA[fi][1].z - mu[fi]) * iv[fi] * rg[1].z + rb[1].z,
        (rA[fi][1].w - mu[fi]) * iv[fi] * rg[1].w + rb[1].w };
      split8(v, ah[fi], al[fi]);
    }
#pragma unroll
    for (int z = 0; z < 3; z++) {
      f32x4 (*ac)[2] = (z == 0) ? aq : ((z == 1) ? ak : av);
#pragma unroll
      for (int fj = 0; fj < 2; fj++) {
        const int n = wn + fj * 16 + r16;
        const int off = boff32(n, q);
        short8 bh = *(const short8*)&cb[(z * 2) * 2048 + off];
        short8 bl = *(const short8*)&cb[(z * 2 + 1) * 2048 + off];
#pragma unroll
        for (int fi = 0; fi < 4; fi++) {
          ac[fi][fj] = MFMA(ah[fi], bh, ac[fi][fj]);
          ac[fi][fj] = MFMA(ah[fi], bl, ac[fi][fj]);
          ac[fi][fj] = MFMA(al[fi], bh, ac[fi][fj]);
        }
      }
    }
#pragma unroll
    for (int fi = 0; fi < 4; fi++) { rA[fi][0] = rB4[fi][0]; rA[fi][1] = rB4[fi][1]; }
    rg[0] = rg2[0]; rg[1] = rg2[1]; rb[0] = rb2[0]; rb[1] = rb2[1];
  }
  __syncthreads();   // arena free for Q/K overlay

  u16 (*Qb)[66] = (u16(*)[66])sm;
  u16 (*Kb)[66] = (u16(*)[66])(sm + 16896);
  {
    const float* bq = a.bias6[0] + l * 512 + head * 64;
    const float* bk = a.bias6[1] + l * 512 + head * 64;
    const float* bv = a.bias6[2] + l * 512 + head * 64;
#pragma unroll
    for (int fi = 0; fi < 4; fi++) {
#pragma unroll
      for (int fj = 0; fj < 2; fj++) {
        const int col = wn + fj * 16 + r16;
        const int row0 = RB[fi] + q * 4;
        const float bqv = bq[col], bkv = bk[col], bvv = bv[col];
#pragma unroll
        for (int i = 0; i < 4; i++) {
          Qb[row0 + i][col] = f2bf(aq[fi][fj][i] + bqv);
          Kb[row0 + i][col] = f2bf(ak[fi][fj][i] + bkv);
          vT[(size_t)col * 128 + row0 + i] = f2bf(av[fi][fj][i] + bvv);
        }
      }
    }
  }
  __syncthreads();

  const int m0 = wave * 32;
  f32x4 sc[2][8] = {};
#pragma unroll
  for (int kk = 0; kk < 2; kk++) {
    short8 aQ[2];
#pragma unroll
    for (int fi = 0; fi < 2; fi++)
      aQ[fi] = *(const short8*)&Qb[m0 + fi * 16 + r16][kk * 32 + q * 8];
#pragma unroll
    for (int nt = 0; nt < 8; nt++) {
      short8 bK = *(const short8*)&Kb[nt * 16 + r16][kk * 32 + q * 8];
#pragma unroll
      for (int fi = 0; fi < 2; fi++) sc[fi][nt] = MFMA(aQ[fi], bK, sc[fi][nt]);
    }
  }
  __syncthreads();

#pragma unroll
  for (int fi = 0; fi < 2; fi++) {
#pragma unroll
    for (int i = 0; i < 4; i++) {
      float mrow = -1e30f;
#pragma unroll
      for (int nt = 0; nt < 8; nt++) {
        float v = sc[fi][nt][i] * 0.125f; sc[fi][nt][i] = v; mrow = fmaxf(mrow, v);
      }
#pragma unroll
      for (int o = 1; o < 16; o <<= 1) mrow = fmaxf(mrow, __shfl_xor(mrow, o, 64));
      float lsum = 0.f;
#pragma unroll
      for (int nt = 0; nt < 8; nt++) {
        float p = __expf(sc[fi][nt][i] - mrow); sc[fi][nt][i] = p; lsum += p;
      }
#pragma unroll
      for (int o = 1; o < 16; o <<= 1) lsum += __shfl_xor(lsum, o, 64);
      const float inv = 1.0f / lsum;
#pragma unroll
      for (int nt = 0; nt < 8; nt++) sc[fi][nt][i] *= inv;
    }
  }
  u16 (*Pb)[132] = (u16(*)[132])sm;
#pragma unroll
  for (int fi = 0; fi < 2; fi++)
#pragma unroll
    for (int nt = 0; nt < 8; nt++)
#pragma unroll
      for (int i = 0; i < 4; i++)
        Pb[m0 + fi * 16 + q * 4 + i][nt * 16 + r16] = f2bf(sc[fi][nt][i]);
  __syncthreads();

  f32x4 oa[2][4] = {};
#pragma unroll
  for (int kt = 0; kt < 4; kt++) {
    short8 aP[2];
#pragma unroll
    for (int fi = 0; fi < 2; fi++)
      aP[fi] = *(const short8*)&Pb[m0 + fi * 16 + r16][kt * 32 + q * 8];
#pragma unroll
    for (int nt = 0; nt < 4; nt++) {
      short8 bV = *(const short8*)(vT + (size_t)(nt * 16 + r16) * 128 + kt * 32 + q * 8);
#pragma unroll
      for (int fi = 0; fi < 2; fi++) oa[fi][nt] = MFMA(aP[fi], bV, oa[fi][nt]);
    }
  }
#pragma unroll
  for (int fi = 0; fi < 2; fi++)
#pragma unroll
    for (int nt = 0; nt < 4; nt++)
#pragma unroll
      for (int i = 0; i < 4; i++) {
        const int row = m0 + fi * 16 + q * 4 + i;
        const int col = head * 64 + nt * 16 + r16;
        float v = oa[fi][nt][i];
        u16 hv = f2bf(v);
        obh_g[(size_t)row * DM + col] = hv;
        obl_g[(size_t)row * DM + col] = f2bf(v - bf2f(hv));
      }
}

// ---------------------------------------------------------------------------
// tileBD: 64x64 split-bf16x3 GEMM, A pre-split from global, 3-deep ring DMA
// with vmcnt/s_barrier pipeline. Stages 0,1 prefetched in preceding barrier.
// ---------------------------------------------------------------------------
template<int EP>
__device__ void tileBD(const u16* Ahi, const u16* Alo, int K,
                       const u16* Whi, const u16* Wlo, const float* bias,
                       int bm, int bn, float* hIO, const float* Xx,
                       float* lnacc, char* sm, int tid)
{
  const int wave = tid >> 6, lane = tid & 63;
  const int q = lane >> 4, r16 = lane & 15;
  const int wm = (wave >> 1) * 32, wn = (wave & 1) * 32;
  const u16* bh0 = Whi + (size_t)bn * K;
  const u16* bl0 = Wlo + (size_t)bn * K;
  f32x4 acc[2][2] = {};
  const int nk = K >> 6;

  short8 cah[2][2], cal[2][2], nh[2][2], nl[2][2];
#pragma unroll
  for (int kk = 0; kk < 2; kk++)
#pragma unroll
    for (int fi = 0; fi < 2; fi++) {
      const size_t ao = (size_t)(bm + wm + fi * 16 + r16) * K + kk * 32 + q * 8;
      cah[kk][fi] = *(const short8*)(Ahi + ao);
      cal[kk][fi] = *(const short8*)(Alo + ao);
    }

  for (int ks = 0; ks < nk; ks++) {
    if (ks + 1 < nk) {                  // A(ks+1): 8 vm-insts
#pragma unroll
      for (int kk = 0; kk < 2; kk++)
#pragma unroll
        for (int fi = 0; fi < 2; fi++) {
          const size_t ao = (size_t)(bm + wm + fi * 16 + r16) * K + (ks + 1) * 64 + kk * 32 + q * 8;
          nh[kk][fi] = *(const short8*)(Ahi + ao);
          nl[kk][fi] = *(const short8*)(Alo + ao);
        }
      __builtin_amdgcn_s_waitcnt(VM12);   // allow A(ks+1)[8]+DMA(ks+1)[4]
    } else {
      __builtin_amdgcn_s_waitcnt(VM0);
    }
    __builtin_amdgcn_s_barrier();
    if (ks + 2 < nk) {                  // DMA(ks+2) -> slot (ks+2)%3
      u16* slot = (u16*)(sm + ((ks + 2) % 3) * 16384);
      dmaW64(bh0, K, (ks + 2) * 64, slot, tid);
      dmaW64(bl0, K, (ks + 2) * 64, slot + 4096, tid);
    }
    const u16* Bsh = (const u16*)(sm + (ks % 3) * 16384);
    const u16* Bsl = Bsh + 4096;
#pragma unroll
    for (int kk = 0; kk < 2; kk++) {
#pragma unroll
      for (int fj = 0; fj < 2; fj++) {
        const int n = wn + fj * 16 + r16;
        const int off = boff64(n, kk * 4 + q);
        short8 bh = *(const short8*)&Bsh[off];
        short8 bl = *(const short8*)&Bsl[off];
#pragma unroll
        for (int fi = 0; fi < 2; fi++) {
          acc[fi][fj] = MFMA(cah[kk][fi], bh, acc[fi][fj]);
          acc[fi][fj] = MFMA(cah[kk][fi], bl, acc[fi][fj]);
          acc[fi][fj] = MFMA(cal[kk][fi], bh, acc[fi][fj]);
        }
      }
    }
#pragma unroll
    for (int kk = 0; kk < 2; kk++)
#pragma unroll
      for (int fi = 0; fi < 2; fi++) { cah[kk][fi] = nh[kk][fi]; cal[kk][fi] = nl[kk][fi]; }
  }

  float outv[2][2][4];
#pragma unroll
  for (int fi = 0; fi < 2; fi++)
#pragma unroll
    for (int fj = 0; fj < 2; fj++) {
      const int col = bn + wn + fj * 16 + r16;
      const float bvv = bias[col];
      const int row0 = bm + wm + fi * 16 + q * 4;
#pragma unroll
      for (int i = 0; i < 4; i++) {
        const size_t off = (size_t)(row0 + i) * DM + col;
        if (EP == EP_RESID) {
          float hv = hIO[off] + acc[fi][fj][i] + bvv;
          hIO[off] = hv; outv[fi][fj][i] = hv;
        } else {
          float hv = hIO[off];
          float hn = 0.5f * hv + 0.5f * tanhf(hv + acc[fi][fj][i] + bvv + Xx[off]);
          hIO[off] = hn; outv[fi][fj][i] = hn;
        }
      }
    }
#pragma unroll
  for (int fi = 0; fi < 2; fi++)
#pragma unroll
    for (int i = 0; i < 4; i++) {
      float a0 = outv[fi][0][i], a1 = outv[fi][1][i];
      float s1 = a0 + a1, s2 = a0 * a0 + a1 * a1;
#pragma unroll
      for (int o = 1; o < 16; o <<= 1) { s1 += __shfl_xor(s1, o, 64); s2 += __shfl_xor(s2, o, 64); }
      if (r16 == 0) {
        const int row = bm + wm + fi * 16 + q * 4 + i;
        atomAddF(&lnacc[row * 2], s1);
        atomAddF(&lnacc[row * 2 + 1], s2);
      }
    }
}

// ---------------------------------------------------------------------------
// tileC2: LN2(atomic stats) + FFN1 + ReLU, two chained 64x64 tiles as one
// 16-stage ring-pipelined loop (weight base switches at stage 8).
// ---------------------------------------------------------------------------
__device__ void tileC2(const KArgs& a, int l, const float* h_g, const float* lnsrc,
                       u16* ffh_g, u16* ffl_g, int bm, int bn0, char* sm, int tid)
{
  const int wave = tid >> 6, lane = tid & 63;
  const int q = lane >> 4, r16 = lane & 15;
  const int wm = (wave >> 1) * 32, wn = (wave & 1) * 32;
  const size_t fOff = (size_t)l * 512 * 1024;
  const float* lg = a.ln2g + l * 512;
  const float* lb = a.ln2b + l * 512;

  float mu[2], iv[2];
#pragma unroll
  for (int fi = 0; fi < 2; fi++) {
    const int rr = bm + wm + fi * 16 + r16;
    const float sv = lnsrc[rr * 2], sq = lnsrc[rr * 2 + 1];
    const float m = sv * (1.0f / 512.0f);
    mu[fi] = m;
    iv[fi] = rsqrtf(sq * (1.0f / 512.0f) - m * m + 1e-5f);
  }

  const u16* whB[2] = { a.WTh[4] + fOff + (size_t)bn0 * 512,
                        a.WTh[4] + fOff + (size_t)(bn0 + 512) * 512 };
  const u16* wlB[2] = { a.WTl[4] + fOff + (size_t)bn0 * 512,
                        a.WTl[4] + fOff + (size_t)(bn0 + 512) * 512 };
  const float* b1 = a.bias6[4] + l * 1024;
  f32x4 acc[2][2] = {};

  float4 rA[2][2][2], rB4[2][2][2], rg[2][2], rb[2][2], rg2[2][2], rb2[2][2];
#pragma unroll
  for (int kk = 0; kk < 2; kk++) {
    const int kb = kk * 32 + q * 8;
#pragma unroll
    for (int fi = 0; fi < 2; fi++) {
      const float* hp = h_g + (size_t)(bm + wm + fi * 16 + r16) * DM + kb;
      rA[kk][fi][0] = *(const float4*)hp; rA[kk][fi][1] = *(const float4*)(hp + 4);
    }
    rg[kk][0] = *(const float4*)&lg[kb]; rg[kk][1] = *(const float4*)&lg[kb + 4];
    rb[kk][0] = *(const float4*)&lb[kb]; rb[kk][1] = *(const float4*)&lb[kb + 4];
  }

  for (int s = 0; s < 16; s++) {
    if (s + 1 < 16) {                   // A(s+1): 16 vm-insts
      const int kb1 = ((s + 1) & 7) * 64;
#pragma unroll
      for (int kk = 0; kk < 2; kk++) {
        const int kb = kb1 + kk * 32 + q * 8;
#pragma unroll
        for (int fi = 0; fi < 2; fi++) {
          const float* hp = h_g + (size_t)(bm + wm + fi * 16 + r16) * DM + kb;
          rB4[kk][fi][0] = *(const float4*)hp; rB4[kk][fi][1] = *(const float4*)(hp + 4);
        }
        rg2[kk][0] = *(const float4*)&lg[kb]; rg2[kk][1] = *(const float4*)&lg[kb + 4];
        rb2[kk][0] = *(const float4*)&lb[kb]; rb2[kk][1] = *(const float4*)&lb[kb + 4];
      }
      __builtin_amdgcn_s_waitcnt(VM20);   // allow A(s+1)[16]+DMA(s+1)[4]
    } else {
      __builtin_amdgcn_s_waitcnt(VM0);
    }
    __builtin_amdgcn_s_barrier();
    if (s + 2 < 16) {
      const int t2 = (s + 2) >> 3, k2 = ((s + 2) & 7) * 64;
      u16* slot = (u16*)(sm + ((s + 2) % 3) * 16384);
      dmaW64(whB[t2], 512, k2, slot, tid);
      dmaW64(wlB[t2], 512, k2, slot + 4096, tid);
    }
    const u16* Bsh = (const u16*)(sm + (s % 3) * 16384);
    const u16* Bsl = Bsh + 4096;
#pragma unroll
    for (int kk = 0; kk < 2; kk++) {
      short8 ah[2], al[2];
#pragma unroll
      for (int fi = 0; fi < 2; fi++) {
        float v[8] = {
          (rA[kk][fi][0].x - mu[fi]) * iv[fi] * rg[kk][0].x + rb[kk][0].x,
          (rA[kk][fi][0].y - mu[fi]) * iv[fi] * rg[kk][0].y + rb[kk][0].y,
          (rA[kk][fi][0].z - mu[fi]) * iv[fi] * rg[kk][0].z + rb[kk][0].z,
          (rA[kk][fi][0].w - mu[fi]) * iv[fi] * rg[kk][0].w + rb[kk][0].w,
          (rA[kk][fi][1].x - mu[fi]) * iv[fi] * rg[kk][1].x + rb[kk][1].x,
          (rA[kk][fi][1].y - mu[fi]) * iv[fi] * rg[kk][1].y + rb[kk][1].y,
          (rA[kk][fi][1].z - mu[fi]) * iv[fi] * rg[kk][1].z + rb[kk][1].z,
          (rA[kk][fi][1].w - mu[fi]) * iv[fi] * rg[kk][1].w + rb[kk][1].w };
        split8(v, ah[fi], al[fi]);
      }
#pragma unroll
      for (int fj = 0; fj < 2; fj++) {
        const int n = wn + fj * 16 + r16;
        const int off = boff64(n, kk * 4 + q);
        short8 bh = *(const short8*)&Bsh[off];
        short8 bl = *(const short8*)&Bsl[off];
#pragma unroll
        for (int fi = 0; fi < 2; fi++) {
          acc[fi][fj] = MFMA(ah[fi], bh, acc[fi][fj]);
          acc[fi][fj] = MFMA(ah[fi], bl, acc[fi][fj]);
          acc[fi][fj] = MFMA(al[fi], bh, acc[fi][fj]);
        }
      }
    }
    if ((s & 7) == 7) {                 // tile (s>>3) epilogue
      const int t = s >> 3;
#pragma unroll
      for (int fi = 0; fi < 2; fi++)
#pragma unroll
        for (int fj = 0; fj < 2; fj++) {
          const int col = bn0 + t * 512 + wn + fj * 16 + r16;
          const float bvv = b1[col];
          const int row0 = bm + wm + fi * 16 + q * 4;
#pragma unroll
          for (int i = 0; i < 4; i++) {
            const size_t off = (size_t)(row0 + i) * 1024 + col;
            float r = fmaxf(acc[fi][fj][i] + bvv, 0.f);
            u16 hv = f2bf(r);
            ffh_g[off] = hv; ffl_g[off] = f2bf(r - bf2f(hv));
          }
          acc[fi][fj] = (f32x4){0.f, 0.f, 0.f, 0.f};
        }
    }
#pragma unroll
    for (int kk = 0; kk < 2; kk++) {
#pragma unroll
      for (int fi = 0; fi < 2; fi++) { rA[kk][fi][0] = rB4[kk][fi][0]; rA[kk][fi][1] = rB4[kk][fi][1]; }
      rg[kk][0] = rg2[kk][0]; rg[kk][1] = rg2[kk][1];
      rb[kk][0] = rb2[kk][0]; rb[kk][1] = rb2[kk][1];
    }
  }
}

// ---------------------------------------------------------------------------
__global__ __launch_bounds__(256, 1) void persist(KArgs a)
{
  __shared__ __align__(16) char smem[SMEM_BYTES];
  const int tid = threadIdx.x;
  const int bid = blockIdx.x;
  const int grp = bid & 7;
  const int gb  = bid >> 3;

  // ---- phase 0: weight split-transpose + embed + zero h + LN sums ----
  {
    float (*tile)[33] = (float (*)[33])smem;
    const int tx = tid & 31, ty = tid >> 5;
    for (int t = bid; t < 4096; t += NB) {
      int tensor, z, k0, n0, K, N;
      if (t < 2048)      { tensor = t >> 9;  int rem = t & 511;  z = rem >> 8; int r2 = rem & 255;
                           K = 512;  N = 512;  k0 = (r2 >> 4) << 5; n0 = (r2 & 15) << 5; }
      else if (t < 3072) { tensor = 4;       int rem = t - 2048; z = rem >> 9; int r2 = rem & 511;
                           K = 512;  N = 1024; k0 = (r2 >> 5) << 5; n0 = (r2 & 31) << 5; }
      else               { tensor = 5;       int rem = t - 3072; z = rem >> 9; int r2 = rem & 511;
                           K = 1024; N = 512;  k0 = (r2 >> 4) << 5; n0 = (r2 & 15) << 5; }
      const float* src = a.W[tensor]   + (size_t)z * K * N;
      u16* dhi         = a.WTh[tensor] + (size_t)z * K * N;
      u16* dlo         = a.WTl[tensor] + (size_t)z * K * N;
      __syncthreads();
#pragma unroll
      for (int r = 0; r < 4; r++) {
        int k = ty + r * 8;
        tile[k][tx] = src[(size_t)(k0 + k) * N + n0 + tx];
      }
      __syncthreads();
#pragma unroll
      for (int r = 0; r < 4; r++) {
        int n = ty + r * 8;
        float w = tile[tx][n];
        u16 hi = f2bf(w);
        dhi[(size_t)(n0 + n) * K + k0 + tx] = hi;
        dlo[(size_t)(n0 + n) * K + k0 + tx] = f2bf(w - bf2f(hi));
      }
    }
    for (int idx = bid * 256 + tid; idx < NTOK * DM; idx += NB * 256) {
      int t = idx >> 9, d = idx & 511, ss = t & 127;
      a.xe[idx] = a.tok[(size_t)a.x[t] * DM + d] + a.pos[ss * DM + d];
      a.h[idx] = 0.0f;
    }
    const int nstat = (41 + 40) * 8 * 256;
    for (int idx = bid * 256 + tid; idx < nstat; idx += NB * 256)
      a.ln1sum[idx] = 0.0f;
  }
  bar_arrive(a.bar + 256, tid);
  if (gb < 8) pfA(a, 0, gb, smem, tid);
  bar_wait(a.bar + 256, NB, tid);

  unsigned* gctr = a.bar + grp * 32;
  unsigned tgt = 0;
  const size_t r512  = (size_t)grp * 128 * 512;
  const size_t r1024 = (size_t)grp * 128 * 1024;
  float* h_g  = a.h  + r512;
  float* xe_g = a.xe + r512;
  u16 *obh_g = a.obh + r512, *obl_g = a.obl + r512;
  u16 *ffh_g = a.ffh + r1024, *ffl_g = a.ffl + r1024;
  const int bn = (gb & 7) * 64, bm = (gb >> 3) * 64;

  for (int it = 0; it < 40; it++) {
    const int l = it & 1;
    const size_t wOff = (size_t)l * 512 * 512;
    const size_t fOff = (size_t)l * 512 * 1024;
    float* ln1it = a.ln1sum + ((size_t)it * 8 + grp) * 256;
    float* ln2it = a.ln2sum + ((size_t)it * 8 + grp) * 256;
    float* ln1nx = a.ln1sum + ((size_t)(it + 1) * 8 + grp) * 256;

    if (gb < 8) phaseA(a, l, gb, grp, ln1it, h_g, obh_g, obl_g, smem, tid);
    bar_arrive(gctr, tid); tgt += 16;
    pfBD2(a.WTh[3] + wOff + (size_t)bn * 512, a.WTl[3] + wOff + (size_t)bn * 512, 512, smem, tid);
    bar_wait(gctr, tgt, tid);

    tileBD<EP_RESID>(obh_g, obl_g, 512, a.WTh[3] + wOff, a.WTl[3] + wOff,
                     a.bias6[3] + l * 512, bm, bn, h_g, nullptr, ln2it, smem, tid);
    bar_arrive(gctr, tid); tgt += 16;
    pfBD2(a.WTh[4] + fOff + (size_t)bn * 512, a.WTl[4] + fOff + (size_t)bn * 512, 512, smem, tid);
    bar_wait(gctr, tgt, tid);

    tileC2(a, l, h_g, ln2it, ffh_g, ffl_g, bm, bn, smem, tid);
    bar_arrive(gctr, tid); tgt += 16;
    pfBD2(a.WTh[5] + fOff + (size_t)bn * 1024, a.WTl[5] + fOff + (size_t)bn * 1024, 1024, smem, tid);
    bar_wait(gctr, tgt, tid);

    tileBD<EP_TANHLERP>(ffh_g, ffl_g, 1024, a.WTh[5] + fOff, a.WTl[5] + fOff,
                        a.bias6[5] + l * 512, bm, bn, h_g, xe_g, ln1nx, smem, tid);
    bar_arrive(gctr, tid); tgt += 16;
    if (it + 1 < 40 && gb < 8) pfA(a, (it + 1) & 1, gb, smem, tid);
    bar_wait(gctr, tgt, tid);
  }

  // group-local mean: hm[grp][512]
  {
    const int dim = gb * 32 + (tid >> 3);
    const int sub = tid & 7;
    float sv = 0.f;
    for (int si = sub; si < 128; si += 8) sv += h_g[(size_t)si * DM + dim];
    sv += __shfl_xor(sv, 1, 64); sv += __shfl_xor(sv, 2, 64); sv += __shfl_xor(sv, 4, 64);
    if (sub == 0) a.hm[grp * 512 + dim] = sv * (1.0f / 128.0f);
  }
  bar_arrive(gctr, tid); tgt += 16;
  bar_wait(gctr, tgt, tid);

  // group-local head: out[grp][1000]
  {
    const int idx = tid >> 2;
    const int n = gb * 63 + idx;
    const int sub = tid & 3;
    if (idx < 63 && n < 1000) {
      const float* hr = a.hm + grp * 512 + sub * 128;
      const float* wr = a.hw + (size_t)(sub * 128) * 1000 + n;
      float sv = 0.f;
      for (int j = 0; j < 128; j++) sv = fmaf(hr[j], wr[(size_t)j * 1000], sv);
      sv += __shfl_xor(sv, 1, 64);
      sv += __shfl_xor(sv, 2, 64);
      if (sub == 0) a.out[grp * 1000 + n] = sv + a.hb[n];
    }
  }
}

// ---------------------------------------------------------------------------
extern "C" void kernel_launch(void* const* d_in, const int* in_sizes, int n_in,
                              void* d_out, int out_size, void* d_ws, size_t ws_size,
                              hipStream_t stream)
{
  (void)in_sizes; (void)n_in; (void)out_size; (void)ws_size;
  KArgs a;
  a.x    = (const int*)d_in[0];
  a.tok  = (const float*)d_in[2];
  a.pos  = (const float*)d_in[3];
  a.W[0] = (const float*)d_in[4];   a.bias6[0] = (const float*)d_in[5];
  a.W[1] = (const float*)d_in[6];   a.bias6[1] = (const float*)d_in[7];
  a.W[2] = (const float*)d_in[8];   a.bias6[2] = (const float*)d_in[9];
  a.W[3] = (const float*)d_in[10];  a.bias6[3] = (const float*)d_in[11];
  a.W[4] = (const float*)d_in[12];  a.bias6[4] = (const float*)d_in[13];
  a.W[5] = (const float*)d_in[14];  a.bias6[5] = (const float*)d_in[15];
  a.ln1g = (const float*)d_in[16];
  a.ln1b = (const float*)d_in[17];
  a.ln2g = (const float*)d_in[18];
  a.ln2b = (const float*)d_in[19];
  a.hw   = (const float*)d_in[20];
  a.hb   = (const float*)d_in[21];
  a.out  = (float*)d_out;

  char* ws = (char*)d_ws;
  const size_t MB = 1ull << 20;
  a.xe   = (float*)(ws + 0 * MB);
  a.h    = (float*)(ws + 2 * MB);
  a.obh  = (u16*)(ws + 4 * MB);
  a.obl  = (u16*)(ws + 5 * MB);
  a.ffh  = (u16*)(ws + 6 * MB);
  a.ffl  = (u16*)(ws + 8 * MB);
  a.hm   = (float*)(ws + 10 * MB);
  a.vT   = (u16*)(ws + 11 * MB);
  a.WTh[0] = (u16*)(ws + 12 * MB);  a.WTl[0] = (u16*)(ws + 13 * MB);
  a.WTh[1] = (u16*)(ws + 14 * MB);  a.WTl[1] = (u16*)(ws + 15 * MB);
  a.WTh[2] = (u16*)(ws + 16 * MB);  a.WTl[2] = (u16*)(ws + 17 * MB);
  a.WTh[3] = (u16*)(ws + 18 * MB);  a.WTl[3] = (u16*)(ws + 19 * MB);
  a.WTh[4] = (u16*)(ws + 20 * MB);  a.WTl[4] = (u16*)(ws + 22 * MB);
  a.WTh[5] = (u16*)(ws + 24 * MB);  a.WTl[5] = (u16*)(ws + 26 * MB);
  a.bar    = (unsigned*)(ws + 28 * MB);
  a.ln1sum = (float*)(ws + 29 * MB);
  a.ln2sum = a.ln1sum + (size_t)41 * 8 * 256;

  bar_init<<<1, 256, 0, stream>>>(a.bar);
  persist<<<NB, 256, 0, stream>>>(a);
}